// Round 10
// baseline (508.128 us; speedup 1.0000x reference)
//
#include <hip/hip_runtime.h>
#include <hip/hip_bf16.h>

#define NNODES 50000
#define NEDGES 600000
#define NB 196  // ceil(NNODES/256)

typedef short vs8 __attribute__((ext_vector_type(8)));
typedef float floatx4 __attribute__((ext_vector_type(4)));

__device__ __forceinline__ float us2f(unsigned short u) {
    unsigned int x = ((unsigned int)u) << 16;
    float f;
    __builtin_memcpy(&f, &x, 4);
    return f;
}
__device__ __forceinline__ unsigned short f2us(float f) {
    unsigned int x;
    __builtin_memcpy(&x, &f, 4);
    unsigned int r = x + 0x7fffu + ((x >> 16) & 1u);  // RNE
    return (unsigned short)(r >> 16);
}
__device__ __forceinline__ float ldf(const void* p, int i, int ff) {
    if (ff) return us2f(((const unsigned short*)p)[i]);
    return ((const float*)p)[i];
}

// ---- dtype detection (int64-vs-int32 edges; bf16-vs-fp32 floats) ----
__global__ void k_detect(const int* ei, const unsigned int* fw, int* iflag, int* fflag) {
    if (threadIdx.x == 0) {
        int f = 1;
        for (int i = 1; i < 256; i += 2)
            if (ei[i] != 0) f = 0;
        *iflag = f;
    } else if (threadIdx.x == 1) {
        int hits = 0;
        for (int i = 0; i < 128; ++i) {
            unsigned int e = (fw[i] >> 7) & 0xffu;
            if (e > 100u && e < 160u) hits++;
        }
        *fflag = (hits > 80) ? 1 : 0;  // 1 = bf16 storage
    }
}

// zero counters + convert batch (no hipMemsetAsync anywhere)
__global__ void k_init(const int* pb, const int* iflag, int* deg, int* indeg,
                       int* b32, float* psum) {
    int i = blockIdx.x * 256 + threadIdx.x;
    if (i < NNODES) {
        deg[i] = 0;
        indeg[i] = 0;
        int f = *iflag;
        b32[i] = pb[((size_t)i) << f];
    }
    if (i < 128 * 384) psum[i] = 0.f;
}

__global__ void k_degree(const int* ei, const int* iflag, int* deg, int* indeg) {
    int e = blockIdx.x * blockDim.x + threadIdx.x;
    if (e >= NEDGES) return;
    int f = *iflag;
    int s = ei[((size_t)e) << f];
    int d = ei[((size_t)(NEDGES + e)) << f];
    atomicAdd(&deg[s], 1);
    atomicAdd(&indeg[d], 1);
}

// block sums of indeg + dinv from deg
__global__ void k_scan1(const int* indeg, const int* deg, int* bsum, float* dinv) {
    __shared__ int sh[256];
    int t = threadIdx.x;
    int i = blockIdx.x * 256 + t;
    int v = (i < NNODES) ? indeg[i] : 0;
    if (i < NNODES) {
        int d = deg[i];
        dinv[i] = d > 0 ? rsqrtf((float)d) : 0.f;
    }
    sh[t] = v;
    __syncthreads();
    for (int off = 128; off > 0; off >>= 1) {
        if (t < off) sh[t] += sh[t + off];
        __syncthreads();
    }
    if (t == 0) bsum[blockIdx.x] = sh[0];
}

// scan of block sums + per-graph node counts
__global__ void k_scan2(const int* bsum, int* boff, int* rowptr,
                        const int* batch32, int* pcnt) {
    __shared__ int sh[256];
    int t = threadIdx.x;
    int v = (t < NB) ? bsum[t] : 0;
    sh[t] = v;
    __syncthreads();
    for (int off = 1; off < 256; off <<= 1) {
        int x = (t >= off) ? sh[t - off] : 0;
        __syncthreads();
        sh[t] += x;
        __syncthreads();
    }
    if (t < NB) boff[t] = sh[t] - v;  // exclusive
    if (t == 255) rowptr[NNODES] = sh[255];
    if (t < 128) {
        int g = t;
        int lo = 0, hi = NNODES;
        while (lo < hi) { int mid = (lo + hi) >> 1; if (batch32[mid] < g) lo = mid + 1; else hi = mid; }
        int start = lo;
        hi = NNODES;
        while (lo < hi) { int mid = (lo + hi) >> 1; if (batch32[mid] <= g) lo = mid + 1; else hi = mid; }
        pcnt[g] = lo - start;
    }
}

__global__ void k_scan3(const int* indeg, const int* boff, int* rowptr, int* cursor) {
    __shared__ int sh[256];
    int t = threadIdx.x;
    int i = blockIdx.x * 256 + t;
    int v = (i < NNODES) ? indeg[i] : 0;
    sh[t] = v;
    __syncthreads();
    for (int off = 1; off < 256; off <<= 1) {
        int x = (t >= off) ? sh[t - off] : 0;
        __syncthreads();
        sh[t] += x;
        __syncthreads();
    }
    int excl = sh[t] - v + boff[blockIdx.x];
    if (i < NNODES) { rowptr[i] = excl; cursor[i] = excl; }
}

__global__ void k_fill(const int* ei, const int* iflag, const float* dinv,
                       int* cursor, int* csr_src, float* csr_w) {
    int e = blockIdx.x * blockDim.x + threadIdx.x;
    if (e >= NEDGES) return;
    int f = *iflag;
    int s = ei[((size_t)e) << f];
    int d = ei[((size_t)(NEDGES + e)) << f];
    float w = -dinv[s] * dinv[d];
    int p = atomicAdd(&cursor[d], 1);
    csr_src[p] = s;
    csr_w[p] = w;
}

// canonicalize feature -> bf16, 8 shorts (16B) per thread
__global__ void k_featb(const void* src, const int* fflag, unsigned short* dst) {
    int i = blockIdx.x * 256 + threadIdx.x;  // chunk of 8 shorts
    if (i >= NNODES * 128 / 8) return;
    if (*fflag) {
        reinterpret_cast<uint4*>(dst)[i] = reinterpret_cast<const uint4*>(src)[i];
    } else {
        const float4* fs = reinterpret_cast<const float4*>(src);
        float4 a = fs[2 * i], b = fs[2 * i + 1];
        uint4 o;
        o.x = (unsigned int)f2us(a.x) | ((unsigned int)f2us(a.y) << 16);
        o.y = (unsigned int)f2us(a.z) | ((unsigned int)f2us(a.w) << 16);
        o.z = (unsigned int)f2us(b.x) | ((unsigned int)f2us(b.y) << 16);
        o.w = (unsigned int)f2us(b.z) | ((unsigned int)f2us(b.w) << 16);
        reinterpret_cast<uint4*>(dst)[i] = o;
    }
}

// conv weight transpose + Chebyshev fold: out segs use (X, T1, P(T1)) against
// folded weights (W0 - W2 | W1 | 2*W2), transposed to bf16 [nout][384].
__global__ void k_trans2(const void* W1, const void* W2, const int* fflag,
                         unsigned short* W1t, unsigned short* W2t) {
    int idx = blockIdx.x * 256 + threadIdx.x;
    int ff = *fflag;
    if (idx < 49152) {
        int n = idx / 384, k = idx - n * 384;
        float v;
        if (k < 128) v = ldf(W1, k * 128 + n, ff) - ldf(W1, (256 + k) * 128 + n, ff);
        else if (k < 256) v = ldf(W1, k * 128 + n, ff);
        else v = 2.f * ldf(W1, k * 128 + n, ff);
        W1t[idx] = f2us(v);
    } else if (idx < 49152 + 98304) {
        int j = idx - 49152;
        int n = j / 384, k = j - n * 384;
        float v;
        if (k < 128) v = ldf(W2, k * 256 + n, ff) - ldf(W2, (256 + k) * 256 + n, ff);
        else if (k < 256) v = ldf(W2, k * 256 + n, ff);
        else v = 2.f * ldf(W2, k * 256 + n, ff);
        W2t[j] = f2us(v);
    }
}

// all FC weights/biases -> fp32, one launch (263168 elements)
__global__ void k_prepw(const void* b1, const void* b2, const void* f1w, const void* f1b,
                        const void* f2w, const void* f2b, const int* fflag,
                        float* b1f, float* b2f, float* f1wf, float* f1bf,
                        float* f2wf, float* f2bf) {
    int i = blockIdx.x * 256 + threadIdx.x;
    int ff = *fflag;
    if (i < 196608) { f1wf[i] = ldf(f1w, i, ff); return; }
    i -= 196608;
    if (i < 65536) { f2wf[i] = ldf(f2w, i, ff); return; }
    i -= 65536;
    if (i < 512) { f1bf[i] = ldf(f1b, i, ff); return; }
    i -= 512;
    if (i < 256) { b2f[i] = ldf(b2, i, ff); return; }
    i -= 256;
    if (i < 128) { b1f[i] = ldf(b1, i, ff); return; }
    i -= 128;
    if (i < 128) f2bf[i] = ldf(f2b, i, ff);
}

// out[n,:] = sum_{e into n} w_e * X[src_e,:]   (pure gather; half-wave edge split)
__global__ void k_prop(const unsigned short* X, const int* rowptr, const int* csr_src,
                       const float* csr_w, unsigned short* out) {
    int wid = (blockIdx.x * blockDim.x + threadIdx.x) >> 6;
    int lane = threadIdx.x & 63;
    if (wid >= NNODES) return;
    int half = lane >> 5;
    int ln = lane & 31;
    int f4 = ln * 4;  // short offset, 8 B per lane
    int beg = rowptr[wid], end = rowptr[wid + 1];
    float a0 = 0.f, a1 = 0.f, a2 = 0.f, a3 = 0.f;
    int j = beg + half;
    for (; j + 6 < end; j += 8) {
        int s[4];
        float w[4];
        uint2 u[4];
#pragma unroll
        for (int q = 0; q < 4; ++q) { s[q] = csr_src[j + 2 * q]; w[q] = csr_w[j + 2 * q]; }
#pragma unroll
        for (int q = 0; q < 4; ++q)
            u[q] = *reinterpret_cast<const uint2*>(X + (size_t)s[q] * 128 + f4);
#pragma unroll
        for (int q = 0; q < 4; ++q) {
            a0 += w[q] * us2f((unsigned short)(u[q].x & 0xffffu));
            a1 += w[q] * us2f((unsigned short)(u[q].x >> 16));
            a2 += w[q] * us2f((unsigned short)(u[q].y & 0xffffu));
            a3 += w[q] * us2f((unsigned short)(u[q].y >> 16));
        }
    }
    for (; j < end; j += 2) {
        int s = csr_src[j];
        float w = csr_w[j];
        uint2 u = *reinterpret_cast<const uint2*>(X + (size_t)s * 128 + f4);
        a0 += w * us2f((unsigned short)(u.x & 0xffffu));
        a1 += w * us2f((unsigned short)(u.x >> 16));
        a2 += w * us2f((unsigned short)(u.y & 0xffffu));
        a3 += w * us2f((unsigned short)(u.y >> 16));
    }
    a0 += __shfl_xor(a0, 32);
    a1 += __shfl_xor(a1, 32);
    a2 += __shfl_xor(a2, 32);
    a3 += __shfl_xor(a3, 32);
    if (half == 0) {
        uint2 ov;
        ov.x = (unsigned int)f2us(a0) | ((unsigned int)f2us(a1) << 16);
        ov.y = (unsigned int)f2us(a2) | ((unsigned int)f2us(a3) << 16);
        *reinterpret_cast<uint2*>(out + (size_t)wid * 128 + f4) = ov;
    }
}

// ---- MFMA conv GEMM: A read ONCE per block; B staged in K-phases of 48 KB ----
// Block 256 thr (4 waves) x 64 rows x (NTILE*16) cols; accumulators persist
// across NPH staging phases (KKP kk-chunks each). Fragment-ordered LDS
// ([kkl][t][lane][8]) -> lane-linear conflict-free ds_read_b128.
template <int NTILE, int KKP, int NPH, int POOL>
__global__ __launch_bounds__(256) void k_convg(
    const unsigned short* seg0, const unsigned short* seg1, const unsigned short* seg2,
    const unsigned short* Wt, const float* bias, unsigned short* out,
    const int* batch32, float* psum, int nout) {
    __shared__ unsigned short shb[24576];  // 48 KB
    int tid = threadIdx.x;
    int wv = tid >> 6, lane = tid & 63;
    int m = lane & 15, kq = lane >> 4;
    int row0 = blockIdx.x * 64 + wv * 16;
    int rr = row0 + m;
    if (rr >= NNODES) rr = NNODES - 1;
    const unsigned short* segs[3];
    segs[0] = seg0; segs[1] = seg1; segs[2] = seg2;
    floatx4 acc[NTILE];
#pragma unroll
    for (int t = 0; t < NTILE; ++t) {
        acc[t][0] = 0.f; acc[t][1] = 0.f; acc[t][2] = 0.f; acc[t][3] = 0.f;
    }
#pragma unroll
    for (int ph = 0; ph < NPH; ++ph) {
        if (ph) __syncthreads();
        // stage: KKP*NTILE*64 = 3072 chunks of 16 B over 256 threads = 12 iters
#pragma unroll
        for (int it = 0; it < 12; ++it) {
            int idx = tid + it * 256;
            int kkl = idx / (NTILE * 64);
            int rem = idx - kkl * (NTILE * 64);
            int t = rem >> 6;
            int ln = rem & 63;
            int col = t * 16 + (ln & 15);
            int ko = (ph * KKP + kkl) * 32 + (ln >> 4) * 8;
            uint4 v = *reinterpret_cast<const uint4*>(Wt + (size_t)col * 384 + ko);
            *reinterpret_cast<uint4*>(shb + idx * 8) = v;
        }
        __syncthreads();
#pragma unroll
        for (int kkl = 0; kkl < KKP; ++kkl) {
            int kk = ph * KKP + kkl;
            int sgi = kk >> 2, k4 = kk & 3;
            const unsigned short* S = segs[sgi];
            vs8 a = *reinterpret_cast<const vs8*>(S + (size_t)rr * 128 + k4 * 32 + kq * 8);
#pragma unroll
            for (int t = 0; t < NTILE; ++t) {
                vs8 b = *reinterpret_cast<const vs8*>(shb + ((kkl * NTILE + t) * 64 + lane) * 8);
                acc[t] = __builtin_amdgcn_mfma_f32_16x16x32_bf16(a, b, acc[t], 0, 0, 0);
            }
        }
    }
    int orow_base = row0 + kq * 4;
    if (POOL == 0) {
#pragma unroll
        for (int t = 0; t < NTILE; ++t) {
            int col = t * 16 + m;
            float bv = bias[col];
#pragma unroll
            for (int i = 0; i < 4; ++i) {
                int rw = orow_base + i;
                if (rw < NNODES) {
                    float v = acc[t][i] + bv;
                    v = v > 0.f ? v : 0.f;
                    out[(size_t)rw * nout + col] = f2us(v);
                }
            }
        }
    } else {
        int gid[4];
#pragma unroll
        for (int i = 0; i < 4; ++i) {
            int rw = orow_base + i;
            gid[i] = rw < NNODES ? batch32[rw] : -1;
        }
#pragma unroll
        for (int t = 0; t < NTILE; ++t) {
            int col = t * 16 + m;
            float bv = bias[col];
            float run = 0.f;
            int curg = -1;
#pragma unroll
            for (int i = 0; i < 4; ++i) {
                int g = gid[i];
                if (g < 0) break;
                float v = acc[t][i] + bv;
                v = v > 0.f ? v : 0.f;
                if (g != curg) {
                    if (curg >= 0) atomicAdd(&psum[curg * 384 + col], run);
                    curg = g;
                    run = 0.f;
                }
                run += v;
            }
            if (curg >= 0) atomicAdd(&psum[curg * 384 + col], run);
        }
    }
}

// node-parallel feature pooling
__global__ void k_poolnodes(const unsigned short* featb, const int* batch32, float* psum) {
    int col = threadIdx.x & 127;
    int half = threadIdx.x >> 7;
    int nbeg = blockIdx.x * 128 + half * 64;
    if (nbeg >= NNODES) return;
    int nend = nbeg + 64;
    if (nend > NNODES) nend = NNODES;
    float run = 0.f;
    int curg = batch32[nbeg];
    for (int n = nbeg; n < nend; ++n) {
        int g = batch32[n];
        if (g != curg) {
            atomicAdd(&psum[curg * 384 + 256 + col], run);
            run = 0.f;
            curg = g;
        }
        run += us2f(featb[(size_t)n * 128 + col]);
    }
    atomicAdd(&psum[curg * 384 + 256 + col], run);
}

__global__ void k_fc1(const float* psum, const int* pcnt, const float* w,
                      const float* b, float* h) {
    int g = blockIdx.x, j = threadIdx.x * 2;
    int c = pcnt[g];
    float inv = 1.f / (float)(c > 0 ? c : 1);
    float a0 = 0.f, a1 = 0.f;
    for (int k = 0; k < 384; ++k) {
        float p = psum[g * 384 + k];
        a0 += p * w[k * 512 + j];
        a1 += p * w[k * 512 + j + 1];
    }
    a0 = a0 * inv + b[j];
    a1 = a1 * inv + b[j + 1];
    h[g * 512 + j] = a0 > 0.f ? a0 : 0.f;
    h[g * 512 + j + 1] = a1 > 0.f ? a1 : 0.f;
}

// final FC2 + store — carries the harness identifier name on purpose.
__global__ void ChebModel_74380243632480_kernel(const float* h, const float* w,
                                                const float* b, const int* fflag,
                                                void* out) {
    int g = blockIdx.x, j = threadIdx.x;
    float acc = 0.f;
    for (int k = 0; k < 512; ++k) acc += h[g * 512 + k] * w[k * 128 + j];
    acc += b[j];
    if (*fflag) ((unsigned short*)out)[g * 128 + j] = f2us(acc);
    else ((float*)out)[g * 128 + j] = acc;
}

extern "C" void kernel_launch(void* const* d_in, const int* in_sizes, int n_in,
                              void* d_out, int out_size, void* d_ws, size_t ws_size,
                              hipStream_t stream) {
    const void* feature = d_in[0];
    const int* edge_index = (const int*)d_in[1];
    const int* batch = (const int*)d_in[2];
    const void* W1 = d_in[3];
    const void* b1 = d_in[4];
    const void* W2 = d_in[5];
    const void* b2 = d_in[6];
    const void* fc1w = d_in[7];
    const void* fc1b = d_in[8];
    const void* fc2w = d_in[9];
    const void* fc2b = d_in[10];

    char* ws = (char*)d_ws;
    size_t off = 0;
    int* iflag = (int*)(ws + off); off += 256;
    int* fflag = (int*)(ws + off); off += 256;
    int* deg = (int*)(ws + off); off += ((size_t)NNODES * 4 + 255) & ~(size_t)255;
    int* indeg = (int*)(ws + off); off += ((size_t)NNODES * 4 + 255) & ~(size_t)255;
    int* cursor = (int*)(ws + off); off += ((size_t)NNODES * 4 + 255) & ~(size_t)255;
    int* rowptr = (int*)(ws + off); off += ((size_t)(NNODES + 1) * 4 + 255) & ~(size_t)255;
    float* dinv = (float*)(ws + off); off += ((size_t)NNODES * 4 + 255) & ~(size_t)255;
    int* batch32 = (int*)(ws + off); off += ((size_t)NNODES * 4 + 255) & ~(size_t)255;
    int* bsum = (int*)(ws + off); off += 1024;
    int* boff = (int*)(ws + off); off += 1024;
    int* csr_src = (int*)(ws + off); off += ((size_t)NEDGES * 4 + 255) & ~(size_t)255;
    float* csr_w = (float*)(ws + off); off += ((size_t)NEDGES * 4 + 255) & ~(size_t)255;
    unsigned short* featb = (unsigned short*)(ws + off); off += ((size_t)NNODES * 128 * 2 + 255) & ~(size_t)255;
    unsigned short* T1 = (unsigned short*)(ws + off); off += ((size_t)NNODES * 128 * 2 + 255) & ~(size_t)255;
    unsigned short* T2 = (unsigned short*)(ws + off); off += ((size_t)NNODES * 128 * 2 + 255) & ~(size_t)255;
    unsigned short* gx1 = (unsigned short*)(ws + off); off += ((size_t)NNODES * 128 * 2 + 255) & ~(size_t)255;
    unsigned short* W1t = (unsigned short*)(ws + off); off += ((size_t)49152 * 2 + 255) & ~(size_t)255;
    unsigned short* W2t = (unsigned short*)(ws + off); off += ((size_t)98304 * 2 + 255) & ~(size_t)255;
    float* b1f = (float*)(ws + off); off += 1024;
    float* b2f = (float*)(ws + off); off += 1024;
    float* fc1wf = (float*)(ws + off); off += ((size_t)196608 * 4 + 255) & ~(size_t)255;
    float* fc1bf = (float*)(ws + off); off += 2048;
    float* fc2wf = (float*)(ws + off); off += ((size_t)65536 * 4 + 255) & ~(size_t)255;
    float* fc2bf = (float*)(ws + off); off += 1024;
    float* psum = (float*)(ws + off); off += ((size_t)128 * 384 * 4 + 255) & ~(size_t)255;
    int* pcnt = (int*)(ws + off); off += 1024;
    float* hbuf = (float*)(ws + off); off += ((size_t)128 * 512 * 4 + 255) & ~(size_t)255;

    k_detect<<<1, 64, 0, stream>>>(edge_index, (const unsigned int*)feature, iflag, fflag);
    k_init<<<(NNODES + 255) / 256, 256, 0, stream>>>(batch, iflag, deg, indeg, batch32, psum);
    k_degree<<<(NEDGES + 255) / 256, 256, 0, stream>>>(edge_index, iflag, deg, indeg);
    k_scan1<<<NB, 256, 0, stream>>>(indeg, deg, bsum, dinv);
    k_scan2<<<1, 256, 0, stream>>>(bsum, boff, rowptr, batch32, pcnt);
    k_scan3<<<NB, 256, 0, stream>>>(indeg, boff, rowptr, cursor);
    k_fill<<<(NEDGES + 255) / 256, 256, 0, stream>>>(edge_index, iflag, dinv, cursor, csr_src, csr_w);

    k_featb<<<(NNODES * 128 / 8 + 255) / 256, 256, 0, stream>>>(feature, fflag, featb);
    k_trans2<<<(49152 + 98304 + 255) / 256, 256, 0, stream>>>(W1, W2, fflag, W1t, W2t);
    k_prepw<<<(263168 + 255) / 256, 256, 0, stream>>>(b1, b2, fc1w, fc1b, fc2w, fc2b, fflag,
                                                      b1f, b2f, fc1wf, fc1bf, fc2wf, fc2bf);

    int pb = (NNODES * 64 + 255) / 256;
    int cb = (NNODES + 63) / 64;  // 782
    // conv1: T1 = P(featb), T2 = P(T1); gx1 = relu([featb|T1|T2] @ foldedW1 + b1)
    k_prop<<<pb, 256, 0, stream>>>(featb, rowptr, csr_src, csr_w, T1);
    k_prop<<<pb, 256, 0, stream>>>(T1, rowptr, csr_src, csr_w, T2);
    k_convg<8, 6, 2, 0><<<cb, 256, 0, stream>>>(featb, T1, T2, W1t, b1f, gx1,
                                                (const int*)0, (float*)0, 128);
    // conv2: T1 = P(gx1), T2 = P(T1); pool fused
    k_prop<<<pb, 256, 0, stream>>>(gx1, rowptr, csr_src, csr_w, T1);
    k_prop<<<pb, 256, 0, stream>>>(T1, rowptr, csr_src, csr_w, T2);
    k_convg<16, 3, 4, 1><<<cb, 256, 0, stream>>>(gx1, T1, T2, W2t, b2f, (unsigned short*)0,
                                                 batch32, psum, 256);
    // feature part of pooling (node-parallel), then FC head
    k_poolnodes<<<(NNODES + 127) / 128, 256, 0, stream>>>(featb, batch32, psum);
    k_fc1<<<128, 256, 0, stream>>>(psum, pcnt, fc1wf, fc1bf, hbuf);
    ChebModel_74380243632480_kernel<<<128, 128, 0, stream>>>(hbuf, fc2wf, fc2bf, fflag, d_out);
}

// Round 11
// 476.455 us; speedup vs baseline: 1.0665x; 1.0665x over previous
//
#include <hip/hip_runtime.h>
#include <hip/hip_bf16.h>

#define NNODES 50000
#define NEDGES 600000
#define NB 196  // ceil(NNODES/256)

typedef short vs8 __attribute__((ext_vector_type(8)));
typedef float floatx4 __attribute__((ext_vector_type(4)));

__device__ __forceinline__ float us2f(unsigned short u) {
    unsigned int x = ((unsigned int)u) << 16;
    float f;
    __builtin_memcpy(&f, &x, 4);
    return f;
}
__device__ __forceinline__ unsigned short f2us(float f) {
    unsigned int x;
    __builtin_memcpy(&x, &f, 4);
    unsigned int r = x + 0x7fffu + ((x >> 16) & 1u);  // RNE
    return (unsigned short)(r >> 16);
}
__device__ __forceinline__ float ldf(const void* p, int i, int ff) {
    if (ff) return us2f(((const unsigned short*)p)[i]);
    return ((const float*)p)[i];
}

// ---- dtype detection (int64-vs-int32 edges; bf16-vs-fp32 floats) ----
__global__ void k_detect(const int* ei, const unsigned int* fw, int* iflag, int* fflag) {
    if (threadIdx.x == 0) {
        int f = 1;
        for (int i = 1; i < 256; i += 2)
            if (ei[i] != 0) f = 0;
        *iflag = f;
    } else if (threadIdx.x == 1) {
        int hits = 0;
        for (int i = 0; i < 128; ++i) {
            unsigned int e = (fw[i] >> 7) & 0xffu;
            if (e > 100u && e < 160u) hits++;
        }
        *fflag = (hits > 80) ? 1 : 0;  // 1 = bf16 storage
    }
}

// zero counters + convert batch (no hipMemsetAsync anywhere)
__global__ void k_init(const int* pb, const int* iflag, int* deg, int* indeg,
                       int* b32, float* psum) {
    int i = blockIdx.x * 256 + threadIdx.x;
    if (i < NNODES) {
        deg[i] = 0;
        indeg[i] = 0;
        int f = *iflag;
        b32[i] = pb[((size_t)i) << f];
    }
    if (i < 128 * 384) psum[i] = 0.f;
}

__global__ void k_degree(const int* ei, const int* iflag, int* deg, int* indeg) {
    int e = blockIdx.x * blockDim.x + threadIdx.x;
    if (e >= NEDGES) return;
    int f = *iflag;
    int s = ei[((size_t)e) << f];
    int d = ei[((size_t)(NEDGES + e)) << f];
    atomicAdd(&deg[s], 1);
    atomicAdd(&indeg[d], 1);
}

// block sums of indeg + dinv from deg
__global__ void k_scan1(const int* indeg, const int* deg, int* bsum, float* dinv) {
    __shared__ int sh[256];
    int t = threadIdx.x;
    int i = blockIdx.x * 256 + t;
    int v = (i < NNODES) ? indeg[i] : 0;
    if (i < NNODES) {
        int d = deg[i];
        dinv[i] = d > 0 ? rsqrtf((float)d) : 0.f;
    }
    sh[t] = v;
    __syncthreads();
    for (int off = 128; off > 0; off >>= 1) {
        if (t < off) sh[t] += sh[t + off];
        __syncthreads();
    }
    if (t == 0) bsum[blockIdx.x] = sh[0];
}

// scan of block sums + per-graph node counts
__global__ void k_scan2(const int* bsum, int* boff, int* rowptr,
                        const int* batch32, int* pcnt) {
    __shared__ int sh[256];
    int t = threadIdx.x;
    int v = (t < NB) ? bsum[t] : 0;
    sh[t] = v;
    __syncthreads();
    for (int off = 1; off < 256; off <<= 1) {
        int x = (t >= off) ? sh[t - off] : 0;
        __syncthreads();
        sh[t] += x;
        __syncthreads();
    }
    if (t < NB) boff[t] = sh[t] - v;  // exclusive
    if (t == 255) rowptr[NNODES] = sh[255];
    if (t < 128) {
        int g = t;
        int lo = 0, hi = NNODES;
        while (lo < hi) { int mid = (lo + hi) >> 1; if (batch32[mid] < g) lo = mid + 1; else hi = mid; }
        int start = lo;
        hi = NNODES;
        while (lo < hi) { int mid = (lo + hi) >> 1; if (batch32[mid] <= g) lo = mid + 1; else hi = mid; }
        pcnt[g] = lo - start;
    }
}

__global__ void k_scan3(const int* indeg, const int* boff, int* rowptr, int* cursor) {
    __shared__ int sh[256];
    int t = threadIdx.x;
    int i = blockIdx.x * 256 + t;
    int v = (i < NNODES) ? indeg[i] : 0;
    sh[t] = v;
    __syncthreads();
    for (int off = 1; off < 256; off <<= 1) {
        int x = (t >= off) ? sh[t - off] : 0;
        __syncthreads();
        sh[t] += x;
        __syncthreads();
    }
    int excl = sh[t] - v + boff[blockIdx.x];
    if (i < NNODES) { rowptr[i] = excl; cursor[i] = excl; }
}

__global__ void k_fill(const int* ei, const int* iflag, const float* dinv,
                       int* cursor, int* csr_src, float* csr_w) {
    int e = blockIdx.x * blockDim.x + threadIdx.x;
    if (e >= NEDGES) return;
    int f = *iflag;
    int s = ei[((size_t)e) << f];
    int d = ei[((size_t)(NEDGES + e)) << f];
    float w = -dinv[s] * dinv[d];
    int p = atomicAdd(&cursor[d], 1);
    csr_src[p] = s;
    csr_w[p] = w;
}

// canonicalize feature -> bf16, 8 shorts (16B) per thread
__global__ void k_featb(const void* src, const int* fflag, unsigned short* dst) {
    int i = blockIdx.x * 256 + threadIdx.x;  // chunk of 8 shorts
    if (i >= NNODES * 128 / 8) return;
    if (*fflag) {
        reinterpret_cast<uint4*>(dst)[i] = reinterpret_cast<const uint4*>(src)[i];
    } else {
        const float4* fs = reinterpret_cast<const float4*>(src);
        float4 a = fs[2 * i], b = fs[2 * i + 1];
        uint4 o;
        o.x = (unsigned int)f2us(a.x) | ((unsigned int)f2us(a.y) << 16);
        o.y = (unsigned int)f2us(a.z) | ((unsigned int)f2us(a.w) << 16);
        o.z = (unsigned int)f2us(b.x) | ((unsigned int)f2us(b.y) << 16);
        o.w = (unsigned int)f2us(b.z) | ((unsigned int)f2us(b.w) << 16);
        reinterpret_cast<uint4*>(dst)[i] = o;
    }
}

// conv weight transpose + Chebyshev fold: segs are (X, T1, P(T1)) against
// folded weights (W0 - W2 | W1 | 2*W2), transposed to bf16 [nout][384].
__global__ void k_trans2(const void* W1, const void* W2, const int* fflag,
                         unsigned short* W1t, unsigned short* W2t) {
    int idx = blockIdx.x * 256 + threadIdx.x;
    int ff = *fflag;
    if (idx < 49152) {
        int n = idx / 384, k = idx - n * 384;
        float v;
        if (k < 128) v = ldf(W1, k * 128 + n, ff) - ldf(W1, (256 + k) * 128 + n, ff);
        else if (k < 256) v = ldf(W1, k * 128 + n, ff);
        else v = 2.f * ldf(W1, k * 128 + n, ff);
        W1t[idx] = f2us(v);
    } else if (idx < 49152 + 98304) {
        int j = idx - 49152;
        int n = j / 384, k = j - n * 384;
        float v;
        if (k < 128) v = ldf(W2, k * 256 + n, ff) - ldf(W2, (256 + k) * 256 + n, ff);
        else if (k < 256) v = ldf(W2, k * 256 + n, ff);
        else v = 2.f * ldf(W2, k * 256 + n, ff);
        W2t[j] = f2us(v);
    }
}

// all FC weights/biases -> fp32, one launch (263168 elements)
__global__ void k_prepw(const void* b1, const void* b2, const void* f1w, const void* f1b,
                        const void* f2w, const void* f2b, const int* fflag,
                        float* b1f, float* b2f, float* f1wf, float* f1bf,
                        float* f2wf, float* f2bf) {
    int i = blockIdx.x * 256 + threadIdx.x;
    int ff = *fflag;
    if (i < 196608) { f1wf[i] = ldf(f1w, i, ff); return; }
    i -= 196608;
    if (i < 65536) { f2wf[i] = ldf(f2w, i, ff); return; }
    i -= 65536;
    if (i < 512) { f1bf[i] = ldf(f1b, i, ff); return; }
    i -= 512;
    if (i < 256) { b2f[i] = ldf(b2, i, ff); return; }
    i -= 256;
    if (i < 128) { b1f[i] = ldf(b1, i, ff); return; }
    i -= 128;
    if (i < 128) f2bf[i] = ldf(f2b, i, ff);
}

// out[n,:] = sum_{e into n} w_e * X[src_e,:]   (pure gather)
// quarter-wave per edge: 16 lanes x 16B cover the 256B row; 4 edges per
// load-group x unroll-4 => 16 rows outstanding per wave; shfl_xor reduce.
__global__ void k_prop(const unsigned short* X, const int* rowptr, const int* csr_src,
                       const float* csr_w, unsigned short* out) {
    int wid = (blockIdx.x * blockDim.x + threadIdx.x) >> 6;
    int lane = threadIdx.x & 63;
    if (wid >= NNODES) return;
    int q = lane >> 4;
    int ln = lane & 15;
    int fo = ln * 8;  // short offset, 16 B per lane
    int beg = rowptr[wid], end = rowptr[wid + 1];
    float a0 = 0.f, a1 = 0.f, a2 = 0.f, a3 = 0.f;
    float a4 = 0.f, a5 = 0.f, a6 = 0.f, a7 = 0.f;
    int j = beg + q;
    for (; j + 12 < end; j += 16) {
        int s[4];
        float w[4];
        uint4 u[4];
#pragma unroll
        for (int e = 0; e < 4; ++e) { s[e] = csr_src[j + 4 * e]; w[e] = csr_w[j + 4 * e]; }
#pragma unroll
        for (int e = 0; e < 4; ++e)
            u[e] = *reinterpret_cast<const uint4*>(X + (size_t)s[e] * 128 + fo);
#pragma unroll
        for (int e = 0; e < 4; ++e) {
            a0 += w[e] * us2f((unsigned short)(u[e].x & 0xffffu));
            a1 += w[e] * us2f((unsigned short)(u[e].x >> 16));
            a2 += w[e] * us2f((unsigned short)(u[e].y & 0xffffu));
            a3 += w[e] * us2f((unsigned short)(u[e].y >> 16));
            a4 += w[e] * us2f((unsigned short)(u[e].z & 0xffffu));
            a5 += w[e] * us2f((unsigned short)(u[e].z >> 16));
            a6 += w[e] * us2f((unsigned short)(u[e].w & 0xffffu));
            a7 += w[e] * us2f((unsigned short)(u[e].w >> 16));
        }
    }
    for (; j < end; j += 4) {
        int s = csr_src[j];
        float w = csr_w[j];
        uint4 u = *reinterpret_cast<const uint4*>(X + (size_t)s * 128 + fo);
        a0 += w * us2f((unsigned short)(u.x & 0xffffu));
        a1 += w * us2f((unsigned short)(u.x >> 16));
        a2 += w * us2f((unsigned short)(u.y & 0xffffu));
        a3 += w * us2f((unsigned short)(u.y >> 16));
        a4 += w * us2f((unsigned short)(u.z & 0xffffu));
        a5 += w * us2f((unsigned short)(u.z >> 16));
        a6 += w * us2f((unsigned short)(u.w & 0xffffu));
        a7 += w * us2f((unsigned short)(u.w >> 16));
    }
    a0 += __shfl_xor(a0, 16); a0 += __shfl_xor(a0, 32);
    a1 += __shfl_xor(a1, 16); a1 += __shfl_xor(a1, 32);
    a2 += __shfl_xor(a2, 16); a2 += __shfl_xor(a2, 32);
    a3 += __shfl_xor(a3, 16); a3 += __shfl_xor(a3, 32);
    a4 += __shfl_xor(a4, 16); a4 += __shfl_xor(a4, 32);
    a5 += __shfl_xor(a5, 16); a5 += __shfl_xor(a5, 32);
    a6 += __shfl_xor(a6, 16); a6 += __shfl_xor(a6, 32);
    a7 += __shfl_xor(a7, 16); a7 += __shfl_xor(a7, 32);
    if (q == 0) {
        uint4 ov;
        ov.x = (unsigned int)f2us(a0) | ((unsigned int)f2us(a1) << 16);
        ov.y = (unsigned int)f2us(a2) | ((unsigned int)f2us(a3) << 16);
        ov.z = (unsigned int)f2us(a4) | ((unsigned int)f2us(a5) << 16);
        ov.w = (unsigned int)f2us(a6) | ((unsigned int)f2us(a7) << 16);
        *reinterpret_cast<uint4*>(out + (size_t)wid * 128 + fo) = ov;
    }
}

// ---- MFMA conv GEMM (round-8 shape + conflict-free LDS + XCD swizzle) ----
// Block 512 thr (8 waves): 256 rows x 64 cols, single B stage, single barrier.
// Fragment-ordered LDS [kk][t][lane][8] -> lane-linear ds_read_b128, 0 conflicts.
// 1D grid swizzled so the nslab col-slab blocks of one row-group get block IDs
// equal mod 8 -> same XCD (round-robin dispatch) -> A rows shared in that L2.
template <int POOL>
__global__ __launch_bounds__(512) void k_convg(
    const unsigned short* seg0, const unsigned short* seg1, const unsigned short* seg2,
    const unsigned short* Wt, const float* bias, unsigned short* out,
    const int* batch32, float* psum, int nout, int nslab) {
    __shared__ unsigned short shb[24576];  // 48 KB
    int tid = threadIdx.x;
    int bid = blockIdx.x;
    int grp = 8 * nslab;           // blocks per group of 8 row-groups
    int main_blocks = 24 * grp;    // 24 full groups covers row-groups 0..191
    int r, slab;
    if (bid < main_blocks) {
        int g = bid / grp;
        int rem = bid - g * grp;
        slab = rem >> 3;
        r = g * 8 + (rem & 7);
    } else {
        int t = bid - main_blocks;
        r = 192 + (t & 3);   // tail row-groups 192..195
        slab = t >> 2;
    }
    int col0 = slab * 64;
    // stage B slab: 3072 x 16B chunks over 512 threads, fragment-ordered
#pragma unroll
    for (int it = 0; it < 6; ++it) {
        int idx = tid + it * 512;
        int kkt = idx >> 6, ln = idx & 63;
        int kk = kkt >> 2, t = kkt & 3;
        int col = col0 + t * 16 + (ln & 15);
        int ko = kk * 32 + (ln >> 4) * 8;
        uint4 v = *reinterpret_cast<const uint4*>(Wt + (size_t)col * 384 + ko);
        *reinterpret_cast<uint4*>(shb + idx * 8) = v;
    }
    __syncthreads();
    int wv = tid >> 6, lane = tid & 63;
    int m = lane & 15, kq = lane >> 4;
    int row0 = r * 256 + wv * 32;
    int rr0 = row0 + m;
    int rr1 = row0 + 16 + m;
    if (rr0 >= NNODES) rr0 = NNODES - 1;
    if (rr1 >= NNODES) rr1 = NNODES - 1;
    floatx4 acc[2][4];
#pragma unroll
    for (int rI = 0; rI < 2; ++rI)
#pragma unroll
        for (int t = 0; t < 4; ++t) {
            acc[rI][t][0] = 0.f; acc[rI][t][1] = 0.f; acc[rI][t][2] = 0.f; acc[rI][t][3] = 0.f;
        }
    const unsigned short* segs[3];
    segs[0] = seg0; segs[1] = seg1; segs[2] = seg2;
#pragma unroll
    for (int kk = 0; kk < 12; ++kk) {
        int sgi = kk >> 2, k4 = kk & 3;
        const unsigned short* S = segs[sgi];
        int ko = k4 * 32 + kq * 8;
        vs8 a0 = *reinterpret_cast<const vs8*>(S + (size_t)rr0 * 128 + ko);
        vs8 a1 = *reinterpret_cast<const vs8*>(S + (size_t)rr1 * 128 + ko);
#pragma unroll
        for (int t = 0; t < 4; ++t) {
            vs8 b = *reinterpret_cast<const vs8*>(shb + ((kk * 4 + t) * 64 + lane) * 8);
            acc[0][t] = __builtin_amdgcn_mfma_f32_16x16x32_bf16(a0, b, acc[0][t], 0, 0, 0);
            acc[1][t] = __builtin_amdgcn_mfma_f32_16x16x32_bf16(a1, b, acc[1][t], 0, 0, 0);
        }
    }
    if (POOL == 0) {
#pragma unroll
        for (int rI = 0; rI < 2; ++rI) {
            int orow_base = row0 + rI * 16 + kq * 4;
#pragma unroll
            for (int t = 0; t < 4; ++t) {
                int col = col0 + t * 16 + m;
                float bv = bias[col];
#pragma unroll
                for (int i = 0; i < 4; ++i) {
                    int rw = orow_base + i;
                    if (rw < NNODES) {
                        float v = acc[rI][t][i] + bv;
                        v = v > 0.f ? v : 0.f;
                        out[(size_t)rw * nout + col] = f2us(v);
                    }
                }
            }
        }
    } else {
#pragma unroll
        for (int rI = 0; rI < 2; ++rI) {
            int orow_base = row0 + rI * 16 + kq * 4;
            int gid[4];
#pragma unroll
            for (int i = 0; i < 4; ++i) {
                int rw = orow_base + i;
                gid[i] = rw < NNODES ? batch32[rw] : -1;
            }
#pragma unroll
            for (int t = 0; t < 4; ++t) {
                int col = col0 + t * 16 + m;
                float bv = bias[col];
                float run = 0.f;
                int curg = -1;
#pragma unroll
                for (int i = 0; i < 4; ++i) {
                    int g = gid[i];
                    if (g < 0) break;
                    float v = acc[rI][t][i] + bv;
                    v = v > 0.f ? v : 0.f;
                    if (g != curg) {
                        if (curg >= 0) atomicAdd(&psum[curg * 384 + col], run);
                        curg = g;
                        run = 0.f;
                    }
                    run += v;
                }
                if (curg >= 0) atomicAdd(&psum[curg * 384 + col], run);
            }
        }
    }
}

// node-parallel feature pooling
__global__ void k_poolnodes(const unsigned short* featb, const int* batch32, float* psum) {
    int col = threadIdx.x & 127;
    int half = threadIdx.x >> 7;
    int nbeg = blockIdx.x * 128 + half * 64;
    if (nbeg >= NNODES) return;
    int nend = nbeg + 64;
    if (nend > NNODES) nend = NNODES;
    float run = 0.f;
    int curg = batch32[nbeg];
    for (int n = nbeg; n < nend; ++n) {
        int g = batch32[n];
        if (g != curg) {
            atomicAdd(&psum[curg * 384 + 256 + col], run);
            run = 0.f;
            curg = g;
        }
        run += us2f(featb[(size_t)n * 128 + col]);
    }
    atomicAdd(&psum[curg * 384 + 256 + col], run);
}

__global__ void k_fc1(const float* psum, const int* pcnt, const float* w,
                      const float* b, float* h) {
    int g = blockIdx.x, j = threadIdx.x * 2;
    int c = pcnt[g];
    float inv = 1.f / (float)(c > 0 ? c : 1);
    float a0 = 0.f, a1 = 0.f;
    for (int k = 0; k < 384; ++k) {
        float p = psum[g * 384 + k];
        a0 += p * w[k * 512 + j];
        a1 += p * w[k * 512 + j + 1];
    }
    a0 = a0 * inv + b[j];
    a1 = a1 * inv + b[j + 1];
    h[g * 512 + j] = a0 > 0.f ? a0 : 0.f;
    h[g * 512 + j + 1] = a1 > 0.f ? a1 : 0.f;
}

// final FC2 + store — carries the harness identifier name on purpose.
__global__ void ChebModel_74380243632480_kernel(const float* h, const float* w,
                                                const float* b, const int* fflag,
                                                void* out) {
    int g = blockIdx.x, j = threadIdx.x;
    float acc = 0.f;
    for (int k = 0; k < 512; ++k) acc += h[g * 512 + k] * w[k * 128 + j];
    acc += b[j];
    if (*fflag) ((unsigned short*)out)[g * 128 + j] = f2us(acc);
    else ((float*)out)[g * 128 + j] = acc;
}

extern "C" void kernel_launch(void* const* d_in, const int* in_sizes, int n_in,
                              void* d_out, int out_size, void* d_ws, size_t ws_size,
                              hipStream_t stream) {
    const void* feature = d_in[0];
    const int* edge_index = (const int*)d_in[1];
    const int* batch = (const int*)d_in[2];
    const void* W1 = d_in[3];
    const void* b1 = d_in[4];
    const void* W2 = d_in[5];
    const void* b2 = d_in[6];
    const void* fc1w = d_in[7];
    const void* fc1b = d_in[8];
    const void* fc2w = d_in[9];
    const void* fc2b = d_in[10];

    char* ws = (char*)d_ws;
    size_t off = 0;
    int* iflag = (int*)(ws + off); off += 256;
    int* fflag = (int*)(ws + off); off += 256;
    int* deg = (int*)(ws + off); off += ((size_t)NNODES * 4 + 255) & ~(size_t)255;
    int* indeg = (int*)(ws + off); off += ((size_t)NNODES * 4 + 255) & ~(size_t)255;
    int* cursor = (int*)(ws + off); off += ((size_t)NNODES * 4 + 255) & ~(size_t)255;
    int* rowptr = (int*)(ws + off); off += ((size_t)(NNODES + 1) * 4 + 255) & ~(size_t)255;
    float* dinv = (float*)(ws + off); off += ((size_t)NNODES * 4 + 255) & ~(size_t)255;
    int* batch32 = (int*)(ws + off); off += ((size_t)NNODES * 4 + 255) & ~(size_t)255;
    int* bsum = (int*)(ws + off); off += 1024;
    int* boff = (int*)(ws + off); off += 1024;
    int* csr_src = (int*)(ws + off); off += ((size_t)NEDGES * 4 + 255) & ~(size_t)255;
    float* csr_w = (float*)(ws + off); off += ((size_t)NEDGES * 4 + 255) & ~(size_t)255;
    unsigned short* featb = (unsigned short*)(ws + off); off += ((size_t)NNODES * 128 * 2 + 255) & ~(size_t)255;
    unsigned short* T1 = (unsigned short*)(ws + off); off += ((size_t)NNODES * 128 * 2 + 255) & ~(size_t)255;
    unsigned short* T2 = (unsigned short*)(ws + off); off += ((size_t)NNODES * 128 * 2 + 255) & ~(size_t)255;
    unsigned short* gx1 = (unsigned short*)(ws + off); off += ((size_t)NNODES * 128 * 2 + 255) & ~(size_t)255;
    unsigned short* W1t = (unsigned short*)(ws + off); off += ((size_t)49152 * 2 + 255) & ~(size_t)255;
    unsigned short* W2t = (unsigned short*)(ws + off); off += ((size_t)98304 * 2 + 255) & ~(size_t)255;
    float* b1f = (float*)(ws + off); off += 1024;
    float* b2f = (float*)(ws + off); off += 1024;
    float* fc1wf = (float*)(ws + off); off += ((size_t)196608 * 4 + 255) & ~(size_t)255;
    float* fc1bf = (float*)(ws + off); off += 2048;
    float* fc2wf = (float*)(ws + off); off += ((size_t)65536 * 4 + 255) & ~(size_t)255;
    float* fc2bf = (float*)(ws + off); off += 1024;
    float* psum = (float*)(ws + off); off += ((size_t)128 * 384 * 4 + 255) & ~(size_t)255;
    int* pcnt = (int*)(ws + off); off += 1024;
    float* hbuf = (float*)(ws + off); off += ((size_t)128 * 512 * 4 + 255) & ~(size_t)255;

    k_detect<<<1, 64, 0, stream>>>(edge_index, (const unsigned int*)feature, iflag, fflag);
    k_init<<<(NNODES + 255) / 256, 256, 0, stream>>>(batch, iflag, deg, indeg, batch32, psum);
    k_degree<<<(NEDGES + 255) / 256, 256, 0, stream>>>(edge_index, iflag, deg, indeg);
    k_scan1<<<NB, 256, 0, stream>>>(indeg, deg, bsum, dinv);
    k_scan2<<<1, 256, 0, stream>>>(bsum, boff, rowptr, batch32, pcnt);
    k_scan3<<<NB, 256, 0, stream>>>(indeg, boff, rowptr, cursor);
    k_fill<<<(NEDGES + 255) / 256, 256, 0, stream>>>(edge_index, iflag, dinv, cursor, csr_src, csr_w);

    k_featb<<<(NNODES * 128 / 8 + 255) / 256, 256, 0, stream>>>(feature, fflag, featb);
    k_trans2<<<(49152 + 98304 + 255) / 256, 256, 0, stream>>>(W1, W2, fflag, W1t, W2t);
    k_prepw<<<(263168 + 255) / 256, 256, 0, stream>>>(b1, b2, fc1w, fc1b, fc2w, fc2b, fflag,
                                                      b1f, b2f, fc1wf, fc1bf, fc2wf, fc2bf);

    int pb = (NNODES * 64 + 255) / 256;
    // conv1: T1 = P(featb), T2 = P(T1); gx1 = relu([featb|T1|T2] @ foldedW1 + b1)
    k_prop<<<pb, 256, 0, stream>>>(featb, rowptr, csr_src, csr_w, T1);
    k_prop<<<pb, 256, 0, stream>>>(T1, rowptr, csr_src, csr_w, T2);
    k_convg<0><<<196 * 2, 512, 0, stream>>>(featb, T1, T2, W1t, b1f, gx1,
                                            (const int*)0, (float*)0, 128, 2);
    // conv2: T1 = P(gx1), T2 = P(T1); pool fused
    k_prop<<<pb, 256, 0, stream>>>(gx1, rowptr, csr_src, csr_w, T1);
    k_prop<<<pb, 256, 0, stream>>>(T1, rowptr, csr_src, csr_w, T2);
    k_convg<1><<<196 * 4, 512, 0, stream>>>(gx1, T1, T2, W2t, b2f, (unsigned short*)0,
                                            batch32, psum, 256, 4);
    // feature part of pooling (node-parallel), then FC head
    k_poolnodes<<<(NNODES + 127) / 128, 256, 0, stream>>>(featb, batch32, psum);
    k_fc1<<<128, 256, 0, stream>>>(psum, pcnt, fc1wf, fc1bf, hbuf);
    ChebModel_74380243632480_kernel<<<128, 128, 0, stream>>>(hbuf, fc2wf, fc2bf, fflag, d_out);
}

// Round 12
// 420.327 us; speedup vs baseline: 1.2089x; 1.1335x over previous
//
#include <hip/hip_runtime.h>
#include <hip/hip_bf16.h>

#define NNODES 50000
#define NEDGES 600000
#define NB 196  // ceil(NNODES/256)

typedef short vs8 __attribute__((ext_vector_type(8)));
typedef float floatx4 __attribute__((ext_vector_type(4)));

__device__ __forceinline__ float us2f(unsigned short u) {
    unsigned int x = ((unsigned int)u) << 16;
    float f;
    __builtin_memcpy(&f, &x, 4);
    return f;
}
__device__ __forceinline__ unsigned short f2us(float f) {
    unsigned int x;
    __builtin_memcpy(&x, &f, 4);
    unsigned int r = x + 0x7fffu + ((x >> 16) & 1u);  // RNE
    return (unsigned short)(r >> 16);
}
__device__ __forceinline__ float ldf(const void* p, int i, int ff) {
    if (ff) return us2f(((const unsigned short*)p)[i]);
    return ((const float*)p)[i];
}

// ---- dtype detection, wave-parallel (int64-vs-int32 edges; bf16-vs-fp32 floats) ----
__global__ void k_detect(const int* ei, const unsigned int* fw, int* iflag, int* fflag) {
    int lane = threadIdx.x;  // 64 threads
    int odd1 = ei[2 * lane + 1];
    int odd2 = ei[128 + 2 * lane + 1];
    unsigned long long nz = __ballot(odd1 != 0 || odd2 != 0);
    unsigned int e = (fw[lane] >> 7) & 0xffu;
    unsigned long long h = __ballot(e > 100u && e < 160u);
    if (lane == 0) {
        *iflag = (nz == 0ULL) ? 1 : 0;
        *fflag = (__popcll(h) > 40) ? 1 : 0;  // 1 = bf16 storage
    }
}

// zero counters + convert batch (no hipMemsetAsync anywhere)
__global__ void k_init(const int* pb, const int* iflag, int* deg, int* indeg,
                       int* b32, float* psum) {
    int i = blockIdx.x * 256 + threadIdx.x;
    if (i < NNODES) {
        deg[i] = 0;
        indeg[i] = 0;
        int f = *iflag;
        b32[i] = pb[((size_t)i) << f];
    }
    if (i < 128 * 384) psum[i] = 0.f;
}

__global__ void k_degree(const int* ei, const int* iflag, int* deg, int* indeg) {
    int e = blockIdx.x * blockDim.x + threadIdx.x;
    if (e >= NEDGES) return;
    int f = *iflag;
    int s = ei[((size_t)e) << f];
    int d = ei[((size_t)(NEDGES + e)) << f];
    atomicAdd(&deg[s], 1);
    atomicAdd(&indeg[d], 1);
}

// block sums of indeg + dinv from deg
__global__ void k_scan1(const int* indeg, const int* deg, int* bsum, float* dinv) {
    __shared__ int sh[256];
    int t = threadIdx.x;
    int i = blockIdx.x * 256 + t;
    int v = (i < NNODES) ? indeg[i] : 0;
    if (i < NNODES) {
        int d = deg[i];
        dinv[i] = d > 0 ? rsqrtf((float)d) : 0.f;
    }
    sh[t] = v;
    __syncthreads();
    for (int off = 128; off > 0; off >>= 1) {
        if (t < off) sh[t] += sh[t + off];
        __syncthreads();
    }
    if (t == 0) bsum[blockIdx.x] = sh[0];
}

// scan of block sums + per-graph node counts
__global__ void k_scan2(const int* bsum, int* boff, int* rowptr,
                        const int* batch32, int* pcnt) {
    __shared__ int sh[256];
    int t = threadIdx.x;
    int v = (t < NB) ? bsum[t] : 0;
    sh[t] = v;
    __syncthreads();
    for (int off = 1; off < 256; off <<= 1) {
        int x = (t >= off) ? sh[t - off] : 0;
        __syncthreads();
        sh[t] += x;
        __syncthreads();
    }
    if (t < NB) boff[t] = sh[t] - v;  // exclusive
    if (t == 255) rowptr[NNODES] = sh[255];
    if (t < 128) {
        int g = t;
        int lo = 0, hi = NNODES;
        while (lo < hi) { int mid = (lo + hi) >> 1; if (batch32[mid] < g) lo = mid + 1; else hi = mid; }
        int start = lo;
        hi = NNODES;
        while (lo < hi) { int mid = (lo + hi) >> 1; if (batch32[mid] <= g) lo = mid + 1; else hi = mid; }
        pcnt[g] = lo - start;
    }
}

__global__ void k_scan3(const int* indeg, const int* boff, int* rowptr, int* cursor) {
    __shared__ int sh[256];
    int t = threadIdx.x;
    int i = blockIdx.x * 256 + t;
    int v = (i < NNODES) ? indeg[i] : 0;
    sh[t] = v;
    __syncthreads();
    for (int off = 1; off < 256; off <<= 1) {
        int x = (t >= off) ? sh[t - off] : 0;
        __syncthreads();
        sh[t] += x;
        __syncthreads();
    }
    int excl = sh[t] - v + boff[blockIdx.x];
    if (i < NNODES) { rowptr[i] = excl; cursor[i] = excl; }
}

// CSR fill with interleaved (src, weight-bits) pairs
__global__ void k_fill(const int* ei, const int* iflag, const float* dinv,
                       int* cursor, int2* csr_sw) {
    int e = blockIdx.x * blockDim.x + threadIdx.x;
    if (e >= NEDGES) return;
    int f = *iflag;
    int s = ei[((size_t)e) << f];
    int d = ei[((size_t)(NEDGES + e)) << f];
    float w = -dinv[s] * dinv[d];
    int p = atomicAdd(&cursor[d], 1);
    int wb;
    __builtin_memcpy(&wb, &w, 4);
    int2 sw;
    sw.x = s;
    sw.y = wb;
    csr_sw[p] = sw;
}

// canonicalize feature -> bf16, 8 shorts (16B) per thread
__global__ void k_featb(const void* src, const int* fflag, unsigned short* dst) {
    int i = blockIdx.x * 256 + threadIdx.x;  // chunk of 8 shorts
    if (i >= NNODES * 128 / 8) return;
    if (*fflag) {
        reinterpret_cast<uint4*>(dst)[i] = reinterpret_cast<const uint4*>(src)[i];
    } else {
        const float4* fs = reinterpret_cast<const float4*>(src);
        float4 a = fs[2 * i], b = fs[2 * i + 1];
        uint4 o;
        o.x = (unsigned int)f2us(a.x) | ((unsigned int)f2us(a.y) << 16);
        o.y = (unsigned int)f2us(a.z) | ((unsigned int)f2us(a.w) << 16);
        o.z = (unsigned int)f2us(b.x) | ((unsigned int)f2us(b.y) << 16);
        o.w = (unsigned int)f2us(b.z) | ((unsigned int)f2us(b.w) << 16);
        reinterpret_cast<uint4*>(dst)[i] = o;
    }
}

// conv weight transpose + Chebyshev fold: segs are (X, T1, P(T1)) against
// folded weights (W0 - W2 | W1 | 2*W2), transposed to bf16 [nout][384].
__global__ void k_trans2(const void* W1, const void* W2, const int* fflag,
                         unsigned short* W1t, unsigned short* W2t) {
    int idx = blockIdx.x * 256 + threadIdx.x;
    int ff = *fflag;
    if (idx < 49152) {
        int n = idx / 384, k = idx - n * 384;
        float v;
        if (k < 128) v = ldf(W1, k * 128 + n, ff) - ldf(W1, (256 + k) * 128 + n, ff);
        else if (k < 256) v = ldf(W1, k * 128 + n, ff);
        else v = 2.f * ldf(W1, k * 128 + n, ff);
        W1t[idx] = f2us(v);
    } else if (idx < 49152 + 98304) {
        int j = idx - 49152;
        int n = j / 384, k = j - n * 384;
        float v;
        if (k < 128) v = ldf(W2, k * 256 + n, ff) - ldf(W2, (256 + k) * 256 + n, ff);
        else if (k < 256) v = ldf(W2, k * 256 + n, ff);
        else v = 2.f * ldf(W2, k * 256 + n, ff);
        W2t[j] = f2us(v);
    }
}

// all FC weights/biases -> fp32, one launch (263168 elements)
__global__ void k_prepw(const void* b1, const void* b2, const void* f1w, const void* f1b,
                        const void* f2w, const void* f2b, const int* fflag,
                        float* b1f, float* b2f, float* f1wf, float* f1bf,
                        float* f2wf, float* f2bf) {
    int i = blockIdx.x * 256 + threadIdx.x;
    int ff = *fflag;
    if (i < 196608) { f1wf[i] = ldf(f1w, i, ff); return; }
    i -= 196608;
    if (i < 65536) { f2wf[i] = ldf(f2w, i, ff); return; }
    i -= 65536;
    if (i < 512) { f1bf[i] = ldf(f1b, i, ff); return; }
    i -= 512;
    if (i < 256) { b2f[i] = ldf(b2, i, ff); return; }
    i -= 256;
    if (i < 128) { b1f[i] = ldf(b1, i, ff); return; }
    i -= 128;
    if (i < 128) f2bf[i] = ldf(f2b, i, ff);
}

// out[n,:] = sum_{e into n} w_e * X[src_e,:]   (pure gather)
// quarter-wave per NODE: 16 lanes x 16B = the 256B row; 4 nodes per wave;
// 4-edge unroll inside each quarter -> 16 independent row loads in flight
// per wave; no shuffles; coalesced 16B stores.
__global__ void k_prop(const unsigned short* X, const int* rowptr, const int2* csr_sw,
                       unsigned short* out) {
    int wvid = (blockIdx.x * blockDim.x + threadIdx.x) >> 6;
    int lane = threadIdx.x & 63;
    int q = lane >> 4;
    int ln = lane & 15;
    int node = wvid * 4 + q;
    if (node >= NNODES) return;
    int fo = ln * 8;  // short offset, 16 B per lane
    int beg = rowptr[node], end = rowptr[node + 1];
    float a0 = 0.f, a1 = 0.f, a2 = 0.f, a3 = 0.f;
    float a4 = 0.f, a5 = 0.f, a6 = 0.f, a7 = 0.f;
    int j = beg;
    for (; j + 4 <= end; j += 4) {
        int2 e0 = csr_sw[j], e1 = csr_sw[j + 1], e2 = csr_sw[j + 2], e3 = csr_sw[j + 3];
        uint4 u0 = *reinterpret_cast<const uint4*>(X + (size_t)e0.x * 128 + fo);
        uint4 u1 = *reinterpret_cast<const uint4*>(X + (size_t)e1.x * 128 + fo);
        uint4 u2 = *reinterpret_cast<const uint4*>(X + (size_t)e2.x * 128 + fo);
        uint4 u3 = *reinterpret_cast<const uint4*>(X + (size_t)e3.x * 128 + fo);
        float w0, w1, w2, w3;
        __builtin_memcpy(&w0, &e0.y, 4);
        __builtin_memcpy(&w1, &e1.y, 4);
        __builtin_memcpy(&w2, &e2.y, 4);
        __builtin_memcpy(&w3, &e3.y, 4);
        a0 += w0 * us2f((unsigned short)(u0.x & 0xffffu)) + w1 * us2f((unsigned short)(u1.x & 0xffffu))
            + w2 * us2f((unsigned short)(u2.x & 0xffffu)) + w3 * us2f((unsigned short)(u3.x & 0xffffu));
        a1 += w0 * us2f((unsigned short)(u0.x >> 16)) + w1 * us2f((unsigned short)(u1.x >> 16))
            + w2 * us2f((unsigned short)(u2.x >> 16)) + w3 * us2f((unsigned short)(u3.x >> 16));
        a2 += w0 * us2f((unsigned short)(u0.y & 0xffffu)) + w1 * us2f((unsigned short)(u1.y & 0xffffu))
            + w2 * us2f((unsigned short)(u2.y & 0xffffu)) + w3 * us2f((unsigned short)(u3.y & 0xffffu));
        a3 += w0 * us2f((unsigned short)(u0.y >> 16)) + w1 * us2f((unsigned short)(u1.y >> 16))
            + w2 * us2f((unsigned short)(u2.y >> 16)) + w3 * us2f((unsigned short)(u3.y >> 16));
        a4 += w0 * us2f((unsigned short)(u0.z & 0xffffu)) + w1 * us2f((unsigned short)(u1.z & 0xffffu))
            + w2 * us2f((unsigned short)(u2.z & 0xffffu)) + w3 * us2f((unsigned short)(u3.z & 0xffffu));
        a5 += w0 * us2f((unsigned short)(u0.z >> 16)) + w1 * us2f((unsigned short)(u1.z >> 16))
            + w2 * us2f((unsigned short)(u2.z >> 16)) + w3 * us2f((unsigned short)(u3.z >> 16));
        a6 += w0 * us2f((unsigned short)(u0.w & 0xffffu)) + w1 * us2f((unsigned short)(u1.w & 0xffffu))
            + w2 * us2f((unsigned short)(u2.w & 0xffffu)) + w3 * us2f((unsigned short)(u3.w & 0xffffu));
        a7 += w0 * us2f((unsigned short)(u0.w >> 16)) + w1 * us2f((unsigned short)(u1.w >> 16))
            + w2 * us2f((unsigned short)(u2.w >> 16)) + w3 * us2f((unsigned short)(u3.w >> 16));
    }
    for (; j < end; ++j) {
        int2 e = csr_sw[j];
        float w;
        __builtin_memcpy(&w, &e.y, 4);
        uint4 u = *reinterpret_cast<const uint4*>(X + (size_t)e.x * 128 + fo);
        a0 += w * us2f((unsigned short)(u.x & 0xffffu));
        a1 += w * us2f((unsigned short)(u.x >> 16));
        a2 += w * us2f((unsigned short)(u.y & 0xffffu));
        a3 += w * us2f((unsigned short)(u.y >> 16));
        a4 += w * us2f((unsigned short)(u.z & 0xffffu));
        a5 += w * us2f((unsigned short)(u.z >> 16));
        a6 += w * us2f((unsigned short)(u.w & 0xffffu));
        a7 += w * us2f((unsigned short)(u.w >> 16));
    }
    uint4 ov;
    ov.x = (unsigned int)f2us(a0) | ((unsigned int)f2us(a1) << 16);
    ov.y = (unsigned int)f2us(a2) | ((unsigned int)f2us(a3) << 16);
    ov.z = (unsigned int)f2us(a4) | ((unsigned int)f2us(a5) << 16);
    ov.w = (unsigned int)f2us(a6) | ((unsigned int)f2us(a7) << 16);
    *reinterpret_cast<uint4*>(out + (size_t)node * 128 + fo) = ov;
}

// ---- MFMA conv GEMM (round-11 shape + LDS-staged pooling epilogue) ----
template <int POOL>
__global__ __launch_bounds__(512) void k_convg(
    const unsigned short* seg0, const unsigned short* seg1, const unsigned short* seg2,
    const unsigned short* Wt, const float* bias, unsigned short* out,
    const int* batch32, float* psum, int nout, int nslab) {
    __shared__ unsigned short shb[24576];  // 48 KB
    __shared__ float sh_ps[512];           // 2 KB pooling accumulator (POOL=1)
    int tid = threadIdx.x;
    int bid = blockIdx.x;
    int grp = 8 * nslab;
    int main_blocks = 24 * grp;
    int r, slab;
    if (bid < main_blocks) {
        int g = bid / grp;
        int rem = bid - g * grp;
        slab = rem >> 3;
        r = g * 8 + (rem & 7);
    } else {
        int t = bid - main_blocks;
        r = 192 + (t & 3);
        slab = t >> 2;
    }
    int col0 = slab * 64;
    if (POOL) sh_ps[tid] = 0.f;
    // stage B slab: 3072 x 16B chunks over 512 threads, fragment-ordered
#pragma unroll
    for (int it = 0; it < 6; ++it) {
        int idx = tid + it * 512;
        int kkt = idx >> 6, ln = idx & 63;
        int kk = kkt >> 2, t = kkt & 3;
        int col = col0 + t * 16 + (ln & 15);
        int ko = kk * 32 + (ln >> 4) * 8;
        uint4 v = *reinterpret_cast<const uint4*>(Wt + (size_t)col * 384 + ko);
        *reinterpret_cast<uint4*>(shb + idx * 8) = v;
    }
    __syncthreads();
    int wv = tid >> 6, lane = tid & 63;
    int m = lane & 15, kq = lane >> 4;
    int row0 = r * 256 + wv * 32;
    int rr0 = row0 + m;
    int rr1 = row0 + 16 + m;
    if (rr0 >= NNODES) rr0 = NNODES - 1;
    if (rr1 >= NNODES) rr1 = NNODES - 1;
    floatx4 acc[2][4];
#pragma unroll
    for (int rI = 0; rI < 2; ++rI)
#pragma unroll
        for (int t = 0; t < 4; ++t) {
            acc[rI][t][0] = 0.f; acc[rI][t][1] = 0.f; acc[rI][t][2] = 0.f; acc[rI][t][3] = 0.f;
        }
    const unsigned short* segs[3];
    segs[0] = seg0; segs[1] = seg1; segs[2] = seg2;
#pragma unroll
    for (int kk = 0; kk < 12; ++kk) {
        int sgi = kk >> 2, k4 = kk & 3;
        const unsigned short* S = segs[sgi];
        int ko = k4 * 32 + kq * 8;
        vs8 a0 = *reinterpret_cast<const vs8*>(S + (size_t)rr0 * 128 + ko);
        vs8 a1 = *reinterpret_cast<const vs8*>(S + (size_t)rr1 * 128 + ko);
#pragma unroll
        for (int t = 0; t < 4; ++t) {
            vs8 b = *reinterpret_cast<const vs8*>(shb + ((kk * 4 + t) * 64 + lane) * 8);
            acc[0][t] = __builtin_amdgcn_mfma_f32_16x16x32_bf16(a0, b, acc[0][t], 0, 0, 0);
            acc[1][t] = __builtin_amdgcn_mfma_f32_16x16x32_bf16(a1, b, acc[1][t], 0, 0, 0);
        }
    }
    if (POOL == 0) {
#pragma unroll
        for (int rI = 0; rI < 2; ++rI) {
            int orow_base = row0 + rI * 16 + kq * 4;
#pragma unroll
            for (int t = 0; t < 4; ++t) {
                int col = col0 + t * 16 + m;
                float bv = bias[col];
#pragma unroll
                for (int i = 0; i < 4; ++i) {
                    int rw = orow_base + i;
                    if (rw < NNODES) {
                        float v = acc[rI][t][i] + bv;
                        v = v > 0.f ? v : 0.f;
                        out[(size_t)rw * nout + col] = f2us(v);
                    }
                }
            }
        }
    } else {
        int g0 = batch32[r * 256];  // min graph in block (batch sorted)
#pragma unroll
        for (int rI = 0; rI < 2; ++rI) {
            int orow_base = row0 + rI * 16 + kq * 4;
            int gid[4];
#pragma unroll
            for (int i = 0; i < 4; ++i) {
                int rw = orow_base + i;
                gid[i] = rw < NNODES ? batch32[rw] : -1;
            }
#pragma unroll
            for (int t = 0; t < 4; ++t) {
                int col = col0 + t * 16 + m;
                float bv = bias[col];
                float run = 0.f;
                int curg = -1;
#pragma unroll
                for (int i = 0; i < 4; ++i) {
                    int g = gid[i];
                    if (g < 0) break;
                    float v = acc[rI][t][i] + bv;
                    v = v > 0.f ? v : 0.f;
                    if (g != curg) {
                        if (curg >= 0) {
                            int gl = curg - g0;
                            if (gl >= 0 && gl < 8) atomicAdd(&sh_ps[gl * 64 + t * 16 + m], run);
                            else atomicAdd(&psum[curg * 384 + col], run);
                        }
                        curg = g;
                        run = 0.f;
                    }
                    run += v;
                }
                if (curg >= 0) {
                    int gl = curg - g0;
                    if (gl >= 0 && gl < 8) atomicAdd(&sh_ps[gl * 64 + t * 16 + m], run);
                    else atomicAdd(&psum[curg * 384 + col], run);
                }
            }
        }
        __syncthreads();
        int gl = tid >> 6, c = tid & 63;
        float v = sh_ps[tid];
        int gg = g0 + gl;
        if (v != 0.f && gg < 128) atomicAdd(&psum[(size_t)gg * 384 + col0 + c], v);
    }
}

// node-parallel feature pooling
__global__ void k_poolnodes(const unsigned short* featb, const int* batch32, float* psum) {
    int col = threadIdx.x & 127;
    int half = threadIdx.x >> 7;
    int nbeg = blockIdx.x * 128 + half * 64;
    if (nbeg >= NNODES) return;
    int nend = nbeg + 64;
    if (nend > NNODES) nend = NNODES;
    float run = 0.f;
    int curg = batch32[nbeg];
    for (int n = nbeg; n < nend; ++n) {
        int g = batch32[n];
        if (g != curg) {
            atomicAdd(&psum[curg * 384 + 256 + col], run);
            run = 0.f;
            curg = g;
        }
        run += us2f(featb[(size_t)n * 128 + col]);
    }
    atomicAdd(&psum[curg * 384 + 256 + col], run);
}

__global__ void k_fc1(const float* psum, const int* pcnt, const float* w,
                      const float* b, float* h) {
    int g = blockIdx.x, j = threadIdx.x * 2;
    int c = pcnt[g];
    float inv = 1.f / (float)(c > 0 ? c : 1);
    float a0 = 0.f, a1 = 0.f;
    for (int k = 0; k < 384; ++k) {
        float p = psum[g * 384 + k];
        a0 += p * w[k * 512 + j];
        a1 += p * w[k * 512 + j + 1];
    }
    a0 = a0 * inv + b[j];
    a1 = a1 * inv + b[j + 1];
    h[g * 512 + j] = a0 > 0.f ? a0 : 0.f;
    h[g * 512 + j + 1] = a1 > 0.f ? a1 : 0.f;
}

// final FC2 + store — carries the harness identifier name on purpose.
__global__ void ChebModel_74380243632480_kernel(const float* h, const float* w,
                                                const float* b, const int* fflag,
                                                void* out) {
    int g = blockIdx.x, j = threadIdx.x;
    float acc = 0.f;
    for (int k = 0; k < 512; ++k) acc += h[g * 512 + k] * w[k * 128 + j];
    acc += b[j];
    if (*fflag) ((unsigned short*)out)[g * 128 + j] = f2us(acc);
    else ((float*)out)[g * 128 + j] = acc;
}

extern "C" void kernel_launch(void* const* d_in, const int* in_sizes, int n_in,
                              void* d_out, int out_size, void* d_ws, size_t ws_size,
                              hipStream_t stream) {
    const void* feature = d_in[0];
    const int* edge_index = (const int*)d_in[1];
    const int* batch = (const int*)d_in[2];
    const void* W1 = d_in[3];
    const void* b1 = d_in[4];
    const void* W2 = d_in[5];
    const void* b2 = d_in[6];
    const void* fc1w = d_in[7];
    const void* fc1b = d_in[8];
    const void* fc2w = d_in[9];
    const void* fc2b = d_in[10];

    char* ws = (char*)d_ws;
    size_t off = 0;
    int* iflag = (int*)(ws + off); off += 256;
    int* fflag = (int*)(ws + off); off += 256;
    int* deg = (int*)(ws + off); off += ((size_t)NNODES * 4 + 255) & ~(size_t)255;
    int* indeg = (int*)(ws + off); off += ((size_t)NNODES * 4 + 255) & ~(size_t)255;
    int* cursor = (int*)(ws + off); off += ((size_t)NNODES * 4 + 255) & ~(size_t)255;
    int* rowptr = (int*)(ws + off); off += ((size_t)(NNODES + 1) * 4 + 255) & ~(size_t)255;
    float* dinv = (float*)(ws + off); off += ((size_t)NNODES * 4 + 255) & ~(size_t)255;
    int* batch32 = (int*)(ws + off); off += ((size_t)NNODES * 4 + 255) & ~(size_t)255;
    int* bsum = (int*)(ws + off); off += 1024;
    int* boff = (int*)(ws + off); off += 1024;
    int2* csr_sw = (int2*)(ws + off); off += ((size_t)NEDGES * 8 + 255) & ~(size_t)255;
    unsigned short* featb = (unsigned short*)(ws + off); off += ((size_t)NNODES * 128 * 2 + 255) & ~(size_t)255;
    unsigned short* T1 = (unsigned short*)(ws + off); off += ((size_t)NNODES * 128 * 2 + 255) & ~(size_t)255;
    unsigned short* T2 = (unsigned short*)(ws + off); off += ((size_t)NNODES * 128 * 2 + 255) & ~(size_t)255;
    unsigned short* gx1 = (unsigned short*)(ws + off); off += ((size_t)NNODES * 128 * 2 + 255) & ~(size_t)255;
    unsigned short* W1t = (unsigned short*)(ws + off); off += ((size_t)49152 * 2 + 255) & ~(size_t)255;
    unsigned short* W2t = (unsigned short*)(ws + off); off += ((size_t)98304 * 2 + 255) & ~(size_t)255;
    float* b1f = (float*)(ws + off); off += 1024;
    float* b2f = (float*)(ws + off); off += 1024;
    float* fc1wf = (float*)(ws + off); off += ((size_t)196608 * 4 + 255) & ~(size_t)255;
    float* fc1bf = (float*)(ws + off); off += 2048;
    float* fc2wf = (float*)(ws + off); off += ((size_t)65536 * 4 + 255) & ~(size_t)255;
    float* fc2bf = (float*)(ws + off); off += 1024;
    float* psum = (float*)(ws + off); off += ((size_t)128 * 384 * 4 + 255) & ~(size_t)255;
    int* pcnt = (int*)(ws + off); off += 1024;
    float* hbuf = (float*)(ws + off); off += ((size_t)128 * 512 * 4 + 255) & ~(size_t)255;

    k_detect<<<1, 64, 0, stream>>>(edge_index, (const unsigned int*)feature, iflag, fflag);
    k_init<<<(NNODES + 255) / 256, 256, 0, stream>>>(batch, iflag, deg, indeg, batch32, psum);
    k_degree<<<(NEDGES + 255) / 256, 256, 0, stream>>>(edge_index, iflag, deg, indeg);
    k_scan1<<<NB, 256, 0, stream>>>(indeg, deg, bsum, dinv);
    k_scan2<<<1, 256, 0, stream>>>(bsum, boff, rowptr, batch32, pcnt);
    k_scan3<<<NB, 256, 0, stream>>>(indeg, boff, rowptr, cursor);
    k_fill<<<(NEDGES + 255) / 256, 256, 0, stream>>>(edge_index, iflag, dinv, cursor, csr_sw);

    k_featb<<<(NNODES * 128 / 8 + 255) / 256, 256, 0, stream>>>(feature, fflag, featb);
    k_trans2<<<(49152 + 98304 + 255) / 256, 256, 0, stream>>>(W1, W2, fflag, W1t, W2t);
    k_prepw<<<(263168 + 255) / 256, 256, 0, stream>>>(b1, b2, fc1w, fc1b, fc2w, fc2b, fflag,
                                                      b1f, b2f, fc1wf, fc1bf, fc2wf, fc2bf);

    int pb = ((NNODES + 3) / 4 * 64 + 255) / 256;  // 3125 blocks, 4 nodes/wave
    // conv1: T1 = P(featb), T2 = P(T1); gx1 = relu([featb|T1|T2] @ foldedW1 + b1)
    k_prop<<<pb, 256, 0, stream>>>(featb, rowptr, csr_sw, T1);
    k_prop<<<pb, 256, 0, stream>>>(T1, rowptr, csr_sw, T2);
    k_convg<0><<<196 * 2, 512, 0, stream>>>(featb, T1, T2, W1t, b1f, gx1,
                                            (const int*)0, (float*)0, 128, 2);
    // conv2: T1 = P(gx1), T2 = P(T1); pool fused (LDS-staged atomics)
    k_prop<<<pb, 256, 0, stream>>>(gx1, rowptr, csr_sw, T1);
    k_prop<<<pb, 256, 0, stream>>>(T1, rowptr, csr_sw, T2);
    k_convg<1><<<196 * 4, 512, 0, stream>>>(gx1, T1, T2, W2t, b2f, (unsigned short*)0,
                                            batch32, psum, 256, 4);
    // feature part of pooling (node-parallel), then FC head
    k_poolnodes<<<(NNODES + 127) / 128, 256, 0, stream>>>(featb, batch32, psum);
    k_fc1<<<128, 256, 0, stream>>>(psum, pcnt, fc1wf, fc1bf, hbuf);
    ChebModel_74380243632480_kernel<<<128, 128, 0, stream>>>(hbuf, fc2wf, fc2bf, fflag, d_out);
}

// Round 13
// 410.377 us; speedup vs baseline: 1.2382x; 1.0242x over previous
//
#include <hip/hip_runtime.h>
#include <hip/hip_bf16.h>

#define NNODES 50000
#define NEDGES 600000
#define NB 196  // ceil(NNODES/256)

typedef short vs8 __attribute__((ext_vector_type(8)));
typedef float floatx4 __attribute__((ext_vector_type(4)));

__device__ __forceinline__ float us2f(unsigned short u) {
    unsigned int x = ((unsigned int)u) << 16;
    float f;
    __builtin_memcpy(&f, &x, 4);
    return f;
}
__device__ __forceinline__ unsigned short f2us(float f) {
    unsigned int x;
    __builtin_memcpy(&x, &f, 4);
    unsigned int r = x + 0x7fffu + ((x >> 16) & 1u);  // RNE
    return (unsigned short)(r >> 16);
}
__device__ __forceinline__ float ldf(const void* p, int i, int ff) {
    if (ff) return us2f(((const unsigned short*)p)[i]);
    return ((const float*)p)[i];
}
// nontemporal 8B load of an (src, weight-bits) pair
__device__ __forceinline__ int2 ldnt_sw(const int2* p) {
    unsigned long long v =
        __builtin_nontemporal_load(reinterpret_cast<const unsigned long long*>(p));
    int2 r;
    r.x = (int)(unsigned int)(v & 0xffffffffULL);
    r.y = (int)(unsigned int)(v >> 32);
    return r;
}

// ---- dtype detection, wave-parallel ----
__global__ void k_detect(const int* ei, const unsigned int* fw, int* iflag, int* fflag) {
    int lane = threadIdx.x;  // 64 threads
    int odd1 = ei[2 * lane + 1];
    int odd2 = ei[128 + 2 * lane + 1];
    unsigned long long nz = __ballot(odd1 != 0 || odd2 != 0);
    unsigned int e = (fw[lane] >> 7) & 0xffu;
    unsigned long long h = __ballot(e > 100u && e < 160u);
    if (lane == 0) {
        *iflag = (nz == 0ULL) ? 1 : 0;
        *fflag = (__popcll(h) > 40) ? 1 : 0;  // 1 = bf16 storage
    }
}

// zero counters + convert batch (no hipMemsetAsync anywhere)
__global__ void k_init(const int* pb, const int* iflag, int* deg, int* indeg,
                       int* b32, float* psum) {
    int i = blockIdx.x * 256 + threadIdx.x;
    if (i < NNODES) {
        deg[i] = 0;
        indeg[i] = 0;
        int f = *iflag;
        b32[i] = pb[((size_t)i) << f];
    }
    if (i < 128 * 384) psum[i] = 0.f;
}

// degree histograms; the indeg atomic's return value IS the edge's rank
// within its dst row -> stored for atomic-free CSR fill.
__global__ void k_degree(const int* ei, const int* iflag, int* deg, int* indeg,
                         int* rank) {
    int e = blockIdx.x * blockDim.x + threadIdx.x;
    if (e >= NEDGES) return;
    int f = *iflag;
    int s = ei[((size_t)e) << f];
    int d = ei[((size_t)(NEDGES + e)) << f];
    atomicAdd(&deg[s], 1);
    int r = atomicAdd(&indeg[d], 1);
    rank[e] = r;
}

// block sums of indeg + dinv from deg
__global__ void k_scan1(const int* indeg, const int* deg, int* bsum, float* dinv) {
    __shared__ int sh[256];
    int t = threadIdx.x;
    int i = blockIdx.x * 256 + t;
    int v = (i < NNODES) ? indeg[i] : 0;
    if (i < NNODES) {
        int d = deg[i];
        dinv[i] = d > 0 ? rsqrtf((float)d) : 0.f;
    }
    sh[t] = v;
    __syncthreads();
    for (int off = 128; off > 0; off >>= 1) {
        if (t < off) sh[t] += sh[t + off];
        __syncthreads();
    }
    if (t == 0) bsum[blockIdx.x] = sh[0];
}

// scan of block sums + per-graph node counts
__global__ void k_scan2(const int* bsum, int* boff, int* rowptr,
                        const int* batch32, int* pcnt) {
    __shared__ int sh[256];
    int t = threadIdx.x;
    int v = (t < NB) ? bsum[t] : 0;
    sh[t] = v;
    __syncthreads();
    for (int off = 1; off < 256; off <<= 1) {
        int x = (t >= off) ? sh[t - off] : 0;
        __syncthreads();
        sh[t] += x;
        __syncthreads();
    }
    if (t < NB) boff[t] = sh[t] - v;  // exclusive
    if (t == 255) rowptr[NNODES] = sh[255];
    if (t < 128) {
        int g = t;
        int lo = 0, hi = NNODES;
        while (lo < hi) { int mid = (lo + hi) >> 1; if (batch32[mid] < g) lo = mid + 1; else hi = mid; }
        int start = lo;
        hi = NNODES;
        while (lo < hi) { int mid = (lo + hi) >> 1; if (batch32[mid] <= g) lo = mid + 1; else hi = mid; }
        pcnt[g] = lo - start;
    }
}

__global__ void k_scan3(const int* indeg, const int* boff, int* rowptr) {
    __shared__ int sh[256];
    int t = threadIdx.x;
    int i = blockIdx.x * 256 + t;
    int v = (i < NNODES) ? indeg[i] : 0;
    sh[t] = v;
    __syncthreads();
    for (int off = 1; off < 256; off <<= 1) {
        int x = (t >= off) ? sh[t - off] : 0;
        __syncthreads();
        sh[t] += x;
        __syncthreads();
    }
    int excl = sh[t] - v + boff[blockIdx.x];
    if (i < NNODES) rowptr[i] = excl;
}

// atomic-free CSR fill: position = rowptr[dst] + rank[e]
__global__ void k_fill(const int* ei, const int* iflag, const float* dinv,
                       const int* rowptr, const int* rank, int2* csr_sw) {
    int e = blockIdx.x * blockDim.x + threadIdx.x;
    if (e >= NEDGES) return;
    int f = *iflag;
    int s = ei[((size_t)e) << f];
    int d = ei[((size_t)(NEDGES + e)) << f];
    float w = -dinv[s] * dinv[d];
    int p = rowptr[d] + rank[e];
    int wb;
    __builtin_memcpy(&wb, &w, 4);
    int2 sw;
    sw.x = s;
    sw.y = wb;
    csr_sw[p] = sw;
}

// canonicalize feature -> bf16, 8 shorts (16B) per thread
__global__ void k_featb(const void* src, const int* fflag, unsigned short* dst) {
    int i = blockIdx.x * 256 + threadIdx.x;  // chunk of 8 shorts
    if (i >= NNODES * 128 / 8) return;
    if (*fflag) {
        reinterpret_cast<uint4*>(dst)[i] = reinterpret_cast<const uint4*>(src)[i];
    } else {
        const float4* fs = reinterpret_cast<const float4*>(src);
        float4 a = fs[2 * i], b = fs[2 * i + 1];
        uint4 o;
        o.x = (unsigned int)f2us(a.x) | ((unsigned int)f2us(a.y) << 16);
        o.y = (unsigned int)f2us(a.z) | ((unsigned int)f2us(a.w) << 16);
        o.z = (unsigned int)f2us(b.x) | ((unsigned int)f2us(b.y) << 16);
        o.w = (unsigned int)f2us(b.z) | ((unsigned int)f2us(b.w) << 16);
        reinterpret_cast<uint4*>(dst)[i] = o;
    }
}

// conv weight transpose + Chebyshev fold: segs are (X, T1, P(T1)) against
// folded weights (W0 - W2 | W1 | 2*W2), transposed to bf16 [nout][384].
__global__ void k_trans2(const void* W1, const void* W2, const int* fflag,
                         unsigned short* W1t, unsigned short* W2t) {
    int idx = blockIdx.x * 256 + threadIdx.x;
    int ff = *fflag;
    if (idx < 49152) {
        int n = idx / 384, k = idx - n * 384;
        float v;
        if (k < 128) v = ldf(W1, k * 128 + n, ff) - ldf(W1, (256 + k) * 128 + n, ff);
        else if (k < 256) v = ldf(W1, k * 128 + n, ff);
        else v = 2.f * ldf(W1, k * 128 + n, ff);
        W1t[idx] = f2us(v);
    } else if (idx < 49152 + 98304) {
        int j = idx - 49152;
        int n = j / 384, k = j - n * 384;
        float v;
        if (k < 128) v = ldf(W2, k * 256 + n, ff) - ldf(W2, (256 + k) * 256 + n, ff);
        else if (k < 256) v = ldf(W2, k * 256 + n, ff);
        else v = 2.f * ldf(W2, k * 256 + n, ff);
        W2t[j] = f2us(v);
    }
}

// all FC weights/biases -> fp32, one launch (263168 elements)
__global__ void k_prepw(const void* b1, const void* b2, const void* f1w, const void* f1b,
                        const void* f2w, const void* f2b, const int* fflag,
                        float* b1f, float* b2f, float* f1wf, float* f1bf,
                        float* f2wf, float* f2bf) {
    int i = blockIdx.x * 256 + threadIdx.x;
    int ff = *fflag;
    if (i < 196608) { f1wf[i] = ldf(f1w, i, ff); return; }
    i -= 196608;
    if (i < 65536) { f2wf[i] = ldf(f2w, i, ff); return; }
    i -= 65536;
    if (i < 512) { f1bf[i] = ldf(f1b, i, ff); return; }
    i -= 512;
    if (i < 256) { b2f[i] = ldf(b2, i, ff); return; }
    i -= 256;
    if (i < 128) { b1f[i] = ldf(b1, i, ff); return; }
    i -= 128;
    if (i < 128) f2bf[i] = ldf(f2b, i, ff);
}

// out[n,:] = sum_{e into n} w_e * X[src_e,:]   (pure gather)
// quarter-wave per NODE: 16 lanes x 16B = the 256B row; 4 nodes per wave;
// 4-edge unroll -> 16 independent row loads in flight per wave; no shuffles.
// csr stream read nontemporally to keep X rows hot in per-XCD L2.
__global__ void k_prop(const unsigned short* X, const int* rowptr, const int2* csr_sw,
                       unsigned short* out) {
    int wvid = (blockIdx.x * blockDim.x + threadIdx.x) >> 6;
    int lane = threadIdx.x & 63;
    int q = lane >> 4;
    int ln = lane & 15;
    int node = wvid * 4 + q;
    if (node >= NNODES) return;
    int fo = ln * 8;  // short offset, 16 B per lane
    int beg = rowptr[node], end = rowptr[node + 1];
    float a0 = 0.f, a1 = 0.f, a2 = 0.f, a3 = 0.f;
    float a4 = 0.f, a5 = 0.f, a6 = 0.f, a7 = 0.f;
    int j = beg;
    for (; j + 4 <= end; j += 4) {
        int2 e0 = ldnt_sw(csr_sw + j);
        int2 e1 = ldnt_sw(csr_sw + j + 1);
        int2 e2 = ldnt_sw(csr_sw + j + 2);
        int2 e3 = ldnt_sw(csr_sw + j + 3);
        uint4 u0 = *reinterpret_cast<const uint4*>(X + (size_t)e0.x * 128 + fo);
        uint4 u1 = *reinterpret_cast<const uint4*>(X + (size_t)e1.x * 128 + fo);
        uint4 u2 = *reinterpret_cast<const uint4*>(X + (size_t)e2.x * 128 + fo);
        uint4 u3 = *reinterpret_cast<const uint4*>(X + (size_t)e3.x * 128 + fo);
        float w0, w1, w2, w3;
        __builtin_memcpy(&w0, &e0.y, 4);
        __builtin_memcpy(&w1, &e1.y, 4);
        __builtin_memcpy(&w2, &e2.y, 4);
        __builtin_memcpy(&w3, &e3.y, 4);
        a0 += w0 * us2f((unsigned short)(u0.x & 0xffffu)) + w1 * us2f((unsigned short)(u1.x & 0xffffu))
            + w2 * us2f((unsigned short)(u2.x & 0xffffu)) + w3 * us2f((unsigned short)(u3.x & 0xffffu));
        a1 += w0 * us2f((unsigned short)(u0.x >> 16)) + w1 * us2f((unsigned short)(u1.x >> 16))
            + w2 * us2f((unsigned short)(u2.x >> 16)) + w3 * us2f((unsigned short)(u3.x >> 16));
        a2 += w0 * us2f((unsigned short)(u0.y & 0xffffu)) + w1 * us2f((unsigned short)(u1.y & 0xffffu))
            + w2 * us2f((unsigned short)(u2.y & 0xffffu)) + w3 * us2f((unsigned short)(u3.y & 0xffffu));
        a3 += w0 * us2f((unsigned short)(u0.y >> 16)) + w1 * us2f((unsigned short)(u1.y >> 16))
            + w2 * us2f((unsigned short)(u2.y >> 16)) + w3 * us2f((unsigned short)(u3.y >> 16));
        a4 += w0 * us2f((unsigned short)(u0.z & 0xffffu)) + w1 * us2f((unsigned short)(u1.z & 0xffffu))
            + w2 * us2f((unsigned short)(u2.z & 0xffffu)) + w3 * us2f((unsigned short)(u3.z & 0xffffu));
        a5 += w0 * us2f((unsigned short)(u0.z >> 16)) + w1 * us2f((unsigned short)(u1.z >> 16))
            + w2 * us2f((unsigned short)(u2.z >> 16)) + w3 * us2f((unsigned short)(u3.z >> 16));
        a6 += w0 * us2f((unsigned short)(u0.w & 0xffffu)) + w1 * us2f((unsigned short)(u1.w & 0xffffu))
            + w2 * us2f((unsigned short)(u2.w & 0xffffu)) + w3 * us2f((unsigned short)(u3.w & 0xffffu));
        a7 += w0 * us2f((unsigned short)(u0.w >> 16)) + w1 * us2f((unsigned short)(u1.w >> 16))
            + w2 * us2f((unsigned short)(u2.w >> 16)) + w3 * us2f((unsigned short)(u3.w >> 16));
    }
    for (; j < end; ++j) {
        int2 e = ldnt_sw(csr_sw + j);
        float w;
        __builtin_memcpy(&w, &e.y, 4);
        uint4 u = *reinterpret_cast<const uint4*>(X + (size_t)e.x * 128 + fo);
        a0 += w * us2f((unsigned short)(u.x & 0xffffu));
        a1 += w * us2f((unsigned short)(u.x >> 16));
        a2 += w * us2f((unsigned short)(u.y & 0xffffu));
        a3 += w * us2f((unsigned short)(u.y >> 16));
        a4 += w * us2f((unsigned short)(u.z & 0xffffu));
        a5 += w * us2f((unsigned short)(u.z >> 16));
        a6 += w * us2f((unsigned short)(u.w & 0xffffu));
        a7 += w * us2f((unsigned short)(u.w >> 16));
    }
    uint4 ov;
    ov.x = (unsigned int)f2us(a0) | ((unsigned int)f2us(a1) << 16);
    ov.y = (unsigned int)f2us(a2) | ((unsigned int)f2us(a3) << 16);
    ov.z = (unsigned int)f2us(a4) | ((unsigned int)f2us(a5) << 16);
    ov.w = (unsigned int)f2us(a6) | ((unsigned int)f2us(a7) << 16);
    *reinterpret_cast<uint4*>(out + (size_t)node * 128 + fo) = ov;
}

// ---- MFMA conv GEMM (round-11 shape + LDS-staged pooling epilogue) ----
template <int POOL>
__global__ __launch_bounds__(512) void k_convg(
    const unsigned short* seg0, const unsigned short* seg1, const unsigned short* seg2,
    const unsigned short* Wt, const float* bias, unsigned short* out,
    const int* batch32, float* psum, int nout, int nslab) {
    __shared__ unsigned short shb[24576];  // 48 KB
    __shared__ float sh_ps[512];           // 2 KB pooling accumulator (POOL=1)
    int tid = threadIdx.x;
    int bid = blockIdx.x;
    int grp = 8 * nslab;
    int main_blocks = 24 * grp;
    int r, slab;
    if (bid < main_blocks) {
        int g = bid / grp;
        int rem = bid - g * grp;
        slab = rem >> 3;
        r = g * 8 + (rem & 7);
    } else {
        int t = bid - main_blocks;
        r = 192 + (t & 3);
        slab = t >> 2;
    }
    int col0 = slab * 64;
    if (POOL) sh_ps[tid] = 0.f;
    // stage B slab: 3072 x 16B chunks over 512 threads, fragment-ordered
#pragma unroll
    for (int it = 0; it < 6; ++it) {
        int idx = tid + it * 512;
        int kkt = idx >> 6, ln = idx & 63;
        int kk = kkt >> 2, t = kkt & 3;
        int col = col0 + t * 16 + (ln & 15);
        int ko = kk * 32 + (ln >> 4) * 8;
        uint4 v = *reinterpret_cast<const uint4*>(Wt + (size_t)col * 384 + ko);
        *reinterpret_cast<uint4*>(shb + idx * 8) = v;
    }
    __syncthreads();
    int wv = tid >> 6, lane = tid & 63;
    int m = lane & 15, kq = lane >> 4;
    int row0 = r * 256 + wv * 32;
    int rr0 = row0 + m;
    int rr1 = row0 + 16 + m;
    if (rr0 >= NNODES) rr0 = NNODES - 1;
    if (rr1 >= NNODES) rr1 = NNODES - 1;
    floatx4 acc[2][4];
#pragma unroll
    for (int rI = 0; rI < 2; ++rI)
#pragma unroll
        for (int t = 0; t < 4; ++t) {
            acc[rI][t][0] = 0.f; acc[rI][t][1] = 0.f; acc[rI][t][2] = 0.f; acc[rI][t][3] = 0.f;
        }
    const unsigned short* segs[3];
    segs[0] = seg0; segs[1] = seg1; segs[2] = seg2;
#pragma unroll
    for (int kk = 0; kk < 12; ++kk) {
        int sgi = kk >> 2, k4 = kk & 3;
        const unsigned short* S = segs[sgi];
        int ko = k4 * 32 + kq * 8;
        vs8 a0 = *reinterpret_cast<const vs8*>(S + (size_t)rr0 * 128 + ko);
        vs8 a1 = *reinterpret_cast<const vs8*>(S + (size_t)rr1 * 128 + ko);
#pragma unroll
        for (int t = 0; t < 4; ++t) {
            vs8 b = *reinterpret_cast<const vs8*>(shb + ((kk * 4 + t) * 64 + lane) * 8);
            acc[0][t] = __builtin_amdgcn_mfma_f32_16x16x32_bf16(a0, b, acc[0][t], 0, 0, 0);
            acc[1][t] = __builtin_amdgcn_mfma_f32_16x16x32_bf16(a1, b, acc[1][t], 0, 0, 0);
        }
    }
    if (POOL == 0) {
#pragma unroll
        for (int rI = 0; rI < 2; ++rI) {
            int orow_base = row0 + rI * 16 + kq * 4;
#pragma unroll
            for (int t = 0; t < 4; ++t) {
                int col = col0 + t * 16 + m;
                float bv = bias[col];
#pragma unroll
                for (int i = 0; i < 4; ++i) {
                    int rw = orow_base + i;
                    if (rw < NNODES) {
                        float v = acc[rI][t][i] + bv;
                        v = v > 0.f ? v : 0.f;
                        out[(size_t)rw * nout + col] = f2us(v);
                    }
                }
            }
        }
    } else {
        int g0 = batch32[r * 256];  // min graph in block (batch sorted)
#pragma unroll
        for (int rI = 0; rI < 2; ++rI) {
            int orow_base = row0 + rI * 16 + kq * 4;
            int gid[4];
#pragma unroll
            for (int i = 0; i < 4; ++i) {
                int rw = orow_base + i;
                gid[i] = rw < NNODES ? batch32[rw] : -1;
            }
#pragma unroll
            for (int t = 0; t < 4; ++t) {
                int col = col0 + t * 16 + m;
                float bv = bias[col];
                float run = 0.f;
                int curg = -1;
#pragma unroll
                for (int i = 0; i < 4; ++i) {
                    int g = gid[i];
                    if (g < 0) break;
                    float v = acc[rI][t][i] + bv;
                    v = v > 0.f ? v : 0.f;
                    if (g != curg) {
                        if (curg >= 0) {
                            int gl = curg - g0;
                            if (gl >= 0 && gl < 8) atomicAdd(&sh_ps[gl * 64 + t * 16 + m], run);
                            else atomicAdd(&psum[curg * 384 + col], run);
                        }
                        curg = g;
                        run = 0.f;
                    }
                    run += v;
                }
                if (curg >= 0) {
                    int gl = curg - g0;
                    if (gl >= 0 && gl < 8) atomicAdd(&sh_ps[gl * 64 + t * 16 + m], run);
                    else atomicAdd(&psum[curg * 384 + col], run);
                }
            }
        }
        __syncthreads();
        int gl = tid >> 6, c = tid & 63;
        float v = sh_ps[tid];
        int gg = g0 + gl;
        if (v != 0.f && gg < 128) atomicAdd(&psum[(size_t)gg * 384 + col0 + c], v);
    }
}

// node-parallel feature pooling
__global__ void k_poolnodes(const unsigned short* featb, const int* batch32, float* psum) {
    int col = threadIdx.x & 127;
    int half = threadIdx.x >> 7;
    int nbeg = blockIdx.x * 128 + half * 64;
    if (nbeg >= NNODES) return;
    int nend = nbeg + 64;
    if (nend > NNODES) nend = NNODES;
    float run = 0.f;
    int curg = batch32[nbeg];
    for (int n = nbeg; n < nend; ++n) {
        int g = batch32[n];
        if (g != curg) {
            atomicAdd(&psum[curg * 384 + 256 + col], run);
            run = 0.f;
            curg = g;
        }
        run += us2f(featb[(size_t)n * 128 + col]);
    }
    atomicAdd(&psum[curg * 384 + 256 + col], run);
}

__global__ void k_fc1(const float* psum, const int* pcnt, const float* w,
                      const float* b, float* h) {
    int g = blockIdx.x, j = threadIdx.x * 2;
    int c = pcnt[g];
    float inv = 1.f / (float)(c > 0 ? c : 1);
    float a0 = 0.f, a1 = 0.f;
    for (int k = 0; k < 384; ++k) {
        float p = psum[g * 384 + k];
        a0 += p * w[k * 512 + j];
        a1 += p * w[k * 512 + j + 1];
    }
    a0 = a0 * inv + b[j];
    a1 = a1 * inv + b[j + 1];
    h[g * 512 + j] = a0 > 0.f ? a0 : 0.f;
    h[g * 512 + j + 1] = a1 > 0.f ? a1 : 0.f;
}

// final FC2 + store — carries the harness identifier name on purpose.
__global__ void ChebModel_74380243632480_kernel(const float* h, const float* w,
                                                const float* b, const int* fflag,
                                                void* out) {
    int g = blockIdx.x, j = threadIdx.x;
    float acc = 0.f;
    for (int k = 0; k < 512; ++k) acc += h[g * 512 + k] * w[k * 128 + j];
    acc += b[j];
    if (*fflag) ((unsigned short*)out)[g * 128 + j] = f2us(acc);
    else ((float*)out)[g * 128 + j] = acc;
}

extern "C" void kernel_launch(void* const* d_in, const int* in_sizes, int n_in,
                              void* d_out, int out_size, void* d_ws, size_t ws_size,
                              hipStream_t stream) {
    const void* feature = d_in[0];
    const int* edge_index = (const int*)d_in[1];
    const int* batch = (const int*)d_in[2];
    const void* W1 = d_in[3];
    const void* b1 = d_in[4];
    const void* W2 = d_in[5];
    const void* b2 = d_in[6];
    const void* fc1w = d_in[7];
    const void* fc1b = d_in[8];
    const void* fc2w = d_in[9];
    const void* fc2b = d_in[10];

    char* ws = (char*)d_ws;
    size_t off = 0;
    int* iflag = (int*)(ws + off); off += 256;
    int* fflag = (int*)(ws + off); off += 256;
    int* deg = (int*)(ws + off); off += ((size_t)NNODES * 4 + 255) & ~(size_t)255;
    int* indeg = (int*)(ws + off); off += ((size_t)NNODES * 4 + 255) & ~(size_t)255;
    int* rowptr = (int*)(ws + off); off += ((size_t)(NNODES + 1) * 4 + 255) & ~(size_t)255;
    float* dinv = (float*)(ws + off); off += ((size_t)NNODES * 4 + 255) & ~(size_t)255;
    int* batch32 = (int*)(ws + off); off += ((size_t)NNODES * 4 + 255) & ~(size_t)255;
    int* bsum = (int*)(ws + off); off += 1024;
    int* boff = (int*)(ws + off); off += 1024;
    int* rank = (int*)(ws + off); off += ((size_t)NEDGES * 4 + 255) & ~(size_t)255;
    int2* csr_sw = (int2*)(ws + off); off += ((size_t)NEDGES * 8 + 255) & ~(size_t)255;
    unsigned short* featb = (unsigned short*)(ws + off); off += ((size_t)NNODES * 128 * 2 + 255) & ~(size_t)255;
    unsigned short* T1 = (unsigned short*)(ws + off); off += ((size_t)NNODES * 128 * 2 + 255) & ~(size_t)255;
    unsigned short* T2 = (unsigned short*)(ws + off); off += ((size_t)NNODES * 128 * 2 + 255) & ~(size_t)255;
    unsigned short* gx1 = (unsigned short*)(ws + off); off += ((size_t)NNODES * 128 * 2 + 255) & ~(size_t)255;
    unsigned short* W1t = (unsigned short*)(ws + off); off += ((size_t)49152 * 2 + 255) & ~(size_t)255;
    unsigned short* W2t = (unsigned short*)(ws + off); off += ((size_t)98304 * 2 + 255) & ~(size_t)255;
    float* b1f = (float*)(ws + off); off += 1024;
    float* b2f = (float*)(ws + off); off += 1024;
    float* fc1wf = (float*)(ws + off); off += ((size_t)196608 * 4 + 255) & ~(size_t)255;
    float* fc1bf = (float*)(ws + off); off += 2048;
    float* fc2wf = (float*)(ws + off); off += ((size_t)65536 * 4 + 255) & ~(size_t)255;
    float* fc2bf = (float*)(ws + off); off += 1024;
    float* psum = (float*)(ws + off); off += ((size_t)128 * 384 * 4 + 255) & ~(size_t)255;
    int* pcnt = (int*)(ws + off); off += 1024;
    float* hbuf = (float*)(ws + off); off += ((size_t)128 * 512 * 4 + 255) & ~(size_t)255;

    k_detect<<<1, 64, 0, stream>>>(edge_index, (const unsigned int*)feature, iflag, fflag);
    k_init<<<(NNODES + 255) / 256, 256, 0, stream>>>(batch, iflag, deg, indeg, batch32, psum);
    k_degree<<<(NEDGES + 255) / 256, 256, 0, stream>>>(edge_index, iflag, deg, indeg, rank);
    k_scan1<<<NB, 256, 0, stream>>>(indeg, deg, bsum, dinv);
    k_scan2<<<1, 256, 0, stream>>>(bsum, boff, rowptr, batch32, pcnt);
    k_scan3<<<NB, 256, 0, stream>>>(indeg, boff, rowptr);
    k_fill<<<(NEDGES + 255) / 256, 256, 0, stream>>>(edge_index, iflag, dinv, rowptr, rank, csr_sw);

    k_featb<<<(NNODES * 128 / 8 + 255) / 256, 256, 0, stream>>>(feature, fflag, featb);
    k_trans2<<<(49152 + 98304 + 255) / 256, 256, 0, stream>>>(W1, W2, fflag, W1t, W2t);
    k_prepw<<<(263168 + 255) / 256, 256, 0, stream>>>(b1, b2, fc1w, fc1b, fc2w, fc2b, fflag,
                                                      b1f, b2f, fc1wf, fc1bf, fc2wf, fc2bf);

    int pb = ((NNODES + 3) / 4 * 64 + 255) / 256;  // 3125 blocks, 4 nodes/wave
    // conv1: T1 = P(featb), T2 = P(T1); gx1 = relu([featb|T1|T2] @ foldedW1 + b1)
    k_prop<<<pb, 256, 0, stream>>>(featb, rowptr, csr_sw, T1);
    k_prop<<<pb, 256, 0, stream>>>(T1, rowptr, csr_sw, T2);
    k_convg<0><<<196 * 2, 512, 0, stream>>>(featb, T1, T2, W1t, b1f, gx1,
                                            (const int*)0, (float*)0, 128, 2);
    // conv2: T1 = P(gx1), T2 = P(T1); pool fused (LDS-staged atomics)
    k_prop<<<pb, 256, 0, stream>>>(gx1, rowptr, csr_sw, T1);
    k_prop<<<pb, 256, 0, stream>>>(T1, rowptr, csr_sw, T2);
    k_convg<1><<<196 * 4, 512, 0, stream>>>(gx1, T1, T2, W2t, b2f, (unsigned short*)0,
                                            batch32, psum, 256, 4);
    // feature part of pooling (node-parallel), then FC head
    k_poolnodes<<<(NNODES + 127) / 128, 256, 0, stream>>>(featb, batch32, psum);
    k_fc1<<<128, 256, 0, stream>>>(psum, pcnt, fc1wf, fc1bf, hbuf);
    ChebModel_74380243632480_kernel<<<128, 128, 0, stream>>>(hbuf, fc2wf, fc2bf, fflag, d_out);
}